// Round 7
// baseline (1098.273 us; speedup 1.0000x reference)
//
#include <hip/hip_runtime.h>
#include <math.h>

#define HH 1024
#define VV 2048
#define BB 256
#define SS 512
#define NSTEPS 6
#define SOS 129
#define L3ROWS 144  // enc rows [0,144) per batch kept L3-resident (147 MB)

typedef __attribute__((ext_vector_type(8))) __bf16 bf16x8;
typedef __attribute__((ext_vector_type(4))) __bf16 bf16x4;
typedef __attribute__((ext_vector_type(2))) __bf16 bf16x2;
typedef __attribute__((ext_vector_type(4))) float f32x4;

__device__ __forceinline__ float sigmoidf_(float x) { return 1.0f / (1.0f + expf(-x)); }

__device__ __forceinline__ void split1(float x, __bf16& h, __bf16& l) {
  h = (__bf16)x;
  l = (__bf16)(x - (float)h);
}

// async global->LDS, 16B per lane; LDS dest must be wave-uniform base.
__device__ __forceinline__ void gll16(const __bf16* src, __bf16* ldst) {
  __builtin_amdgcn_global_load_lds(
      (const __attribute__((address_space(1))) unsigned*)(const void*)src,
      (__attribute__((address_space(3))) unsigned*)(void*)ldst, 16, 0, 0);
}

// ---------------------------------------------------------------------------
// Split-bf16 MFMA GEMM, double-buffered, global_load_lds staging, SPLIT-K,
// XCD-aware 1-D grid decode (kept from R6; neutral but harmless).
// P[z][m][n] = sum_{k in chunk z} A[m][k]*B[n][k]  (raw fp32 partials).
// Tile 64x64, BK=64, 256 threads (4 waves), wave-tile 32x32.
// AMODE 0: A = Ah/Al, row stride lda.
// AMODE 1: A = [emb[aidx[r]] | hcat[r][0:1024]] (gates GEMM, K=2048).
// ---------------------------------------------------------------------------
template<int AMODE>
__global__ __launch_bounds__(256) void gemm3(
    const __bf16* __restrict__ Ah, const __bf16* __restrict__ Al, int lda,
    const __bf16* __restrict__ A1h, const __bf16* __restrict__ A1l,
    const int* __restrict__ aidx,
    const __bf16* __restrict__ Bh, const __bf16* __restrict__ Bl, int K,
    int kLen, float* __restrict__ P, int ldc,
    int ny, int nz)
{
  __shared__ __align__(16) __bf16 lds[2][4][64 * 64];  // 64 KB
  const int t = threadIdx.x, lane = t & 63, wv = t >> 6;

  // XCD-chunked decode, x-major work order (all y,z of an x share an XCD)
  const int chunk = (int)(gridDim.x >> 3);
  const int w = (blockIdx.x & 7) * chunk + (blockIdx.x >> 3);
  const int bz = w % nz;
  const int by = (w / nz) % ny;
  const int bx = w / (nz * ny);

  const int row0 = by * 64, col0 = bx * 64;

  const int sslot = lane & 7;
  const int srw   = lane >> 3;
  int sw[2];
  const __bf16 *arh[2], *arl[2], *a1h[2], *a1l[2], *brh[2], *brl[2];
#pragma unroll
  for (int hf = 0; hf < 2; ++hf) {
    const int tr = wv * 16 + hf * 8 + srw;
    sw[hf] = (sslot ^ (tr & 7)) << 3;
    const int ar = row0 + tr;
    if (AMODE == 1) {
      const int r = aidx[ar];
      arh[hf] = Ah + (size_t)r * HH;
      arl[hf] = Al + (size_t)r * HH;
      a1h[hf] = A1h + (size_t)ar * 2048;
      a1l[hf] = A1l + (size_t)ar * 2048;
    } else {
      arh[hf] = Ah + (size_t)ar * lda;
      arl[hf] = Al + (size_t)ar * lda;
    }
    const int br = col0 + tr;
    brh[hf] = Bh + (size_t)br * K;
    brl[hf] = Bl + (size_t)br * K;
  }

  const int wr = (wv >> 1) * 32, wc = (wv & 1) * 32;
  const int fr = lane & 15, kb = (lane >> 4) * 8;

  const f32x4 fz = {0.f, 0.f, 0.f, 0.f};
  f32x4 acc[2][2] = {{fz, fz}, {fz, fz}};

  const int tBeg = (bz * kLen) >> 6;
  const int nt = kLen >> 6;

  auto stage = [&](int tIdx, int bi) {
    const int k0 = tIdx << 6;
#pragma unroll
    for (int hf = 0; hf < 2; ++hf) {
      const int rb = (wv * 16 + hf * 8) * 64;
      const __bf16 *sa_h, *sa_l;
      if (AMODE == 1 && k0 >= HH) {
        sa_h = a1h[hf] + (k0 - HH) + sw[hf];
        sa_l = a1l[hf] + (k0 - HH) + sw[hf];
      } else {
        sa_h = arh[hf] + k0 + sw[hf];
        sa_l = arl[hf] + k0 + sw[hf];
      }
      gll16(sa_h, &lds[bi][0][rb]);
      gll16(sa_l, &lds[bi][1][rb]);
      gll16(brh[hf] + k0 + sw[hf], &lds[bi][2][rb]);
      gll16(brl[hf] + k0 + sw[hf], &lds[bi][3][rb]);
    }
  };

  auto compute = [&](int bi) {
#pragma unroll
    for (int kc = 0; kc < 2; ++kc) {
      const int e = kc * 32 + kb;
      bf16x8 a_h[2], a_l[2], b_h[2], b_l[2];
#pragma unroll
      for (int i = 0; i < 2; ++i) {
        const int ra = wr + i * 16 + fr;
        const int ia = ra * 64 + (e ^ ((ra & 7) << 3));
        a_h[i] = *(const bf16x8*)&lds[bi][0][ia];
        a_l[i] = *(const bf16x8*)&lds[bi][1][ia];
        const int rb2 = wc + i * 16 + fr;
        const int ib = rb2 * 64 + (e ^ ((rb2 & 7) << 3));
        b_h[i] = *(const bf16x8*)&lds[bi][2][ib];
        b_l[i] = *(const bf16x8*)&lds[bi][3][ib];
      }
#pragma unroll
      for (int i = 0; i < 2; ++i)
#pragma unroll
        for (int j = 0; j < 2; ++j)
          acc[i][j] = __builtin_amdgcn_mfma_f32_16x16x32_bf16(a_h[i], b_h[j], acc[i][j], 0, 0, 0);
#pragma unroll
      for (int i = 0; i < 2; ++i)
#pragma unroll
        for (int j = 0; j < 2; ++j)
          acc[i][j] = __builtin_amdgcn_mfma_f32_16x16x32_bf16(a_h[i], b_l[j], acc[i][j], 0, 0, 0);
#pragma unroll
      for (int i = 0; i < 2; ++i)
#pragma unroll
        for (int j = 0; j < 2; ++j)
          acc[i][j] = __builtin_amdgcn_mfma_f32_16x16x32_bf16(a_l[i], b_h[j], acc[i][j], 0, 0, 0);
    }
  };

  stage(tBeg, 0);
  __syncthreads();
  int cur = 0;
  for (int tk = 0; tk < nt; ++tk) {
    if (tk + 1 < nt) stage(tBeg + tk + 1, cur ^ 1);
    compute(cur);
    __syncthreads();
    cur ^= 1;
  }

  float* Cp = P + (size_t)bz * 256 * ldc;
#pragma unroll
  for (int i = 0; i < 2; ++i)
#pragma unroll
    for (int j = 0; j < 2; ++j) {
      const int col = col0 + wc + j * 16 + fr;
#pragma unroll
      for (int r = 0; r < 4; ++r) {
        const int row = row0 + wr + i * 16 + (lane >> 4) * 4 + r;
        Cp[(size_t)row * ldc + col] = acc[i][j][r];
      }
    }
}

// ---------------------------------------------------------------------------
// One-shot conversion of all fp32 weights (+ embedding) to split hi/lo bf16.
// ---------------------------------------------------------------------------
__global__ __launch_bounds__(256) void conv_all(
    const float* __restrict__ W_ih, const float* __restrict__ W_hh,
    const float* __restrict__ attn_W, const float* __restrict__ concat_W,
    const float* __restrict__ lin_W, const float* __restrict__ emb,
    __bf16* __restrict__ Wcat_h, __bf16* __restrict__ Wcat_l,
    __bf16* __restrict__ attnW_h, __bf16* __restrict__ attnW_l,
    __bf16* __restrict__ catW_h, __bf16* __restrict__ catW_l,
    __bf16* __restrict__ linW_h, __bf16* __restrict__ linW_l,
    __bf16* __restrict__ emb_h, __bf16* __restrict__ emb_l)
{
  const int i = blockIdx.x * 256 + threadIdx.x;
  const float* s;
  __bf16 *dh, *dl;
  size_t so, dofs;
  if (i < 2097152) {
    const int ii = i & 1048575;
    const int r = ii >> 8, cp = (ii & 255) << 2;
    s = (i < 1048576) ? W_ih : W_hh;
    so = (size_t)r * 1024 + cp;
    dh = Wcat_h; dl = Wcat_l;
    dofs = (size_t)r * 2048 + ((i < 1048576) ? 0 : 1024) + cp;
  } else if (i < 2359296) {
    const size_t ii = (size_t)(i - 2097152) << 2;
    s = attn_W; so = ii; dh = attnW_h; dl = attnW_l; dofs = ii;
  } else if (i < 2883584) {
    const size_t ii = (size_t)(i - 2359296) << 2;
    s = concat_W; so = ii; dh = catW_h; dl = catW_l; dofs = ii;
  } else if (i < 3407872) {
    const size_t ii = (size_t)(i - 2883584) << 2;
    s = lin_W; so = ii; dh = linW_h; dl = linW_l; dofs = ii;
  } else {
    const size_t ii = (size_t)(i - 3407872) << 2;
    s = emb; so = ii; dh = emb_h; dl = emb_l; dofs = ii;
  }
  const float4 v = *(const float4*)(s + so);
  __bf16 h0, l0, h1, l1, h2, l2, h3, l3;
  split1(v.x, h0, l0); split1(v.y, h1, l1); split1(v.z, h2, l2); split1(v.w, h3, l3);
  *(bf16x4*)&dh[dofs] = bf16x4{h0, h1, h2, h3};
  *(bf16x4*)&dl[dofs] = bf16x4{l0, l1, l2, l3};
}

// ---------------------------------------------------------------------------
// gates reduce (2 split-K chunks) + bias + LSTM elementwise; emits h split.
// ---------------------------------------------------------------------------
__global__ __launch_bounds__(256) void lstm_reduce(
    const float* __restrict__ Pg, const float* __restrict__ bihh,
    float* c, float* h,
    __bf16* __restrict__ hcat_h, __bf16* __restrict__ hcat_l)
{
  const int id = blockIdx.x * 256 + threadIdx.x;  // 0..262143
  const int b = id >> 10, j = id & 1023;
  const size_t base = (size_t)b * 4096 + j;
  const size_t cs = (size_t)256 * 4096;
  const float ig = Pg[base]        + Pg[base + cs]        + bihh[j];
  const float fg = Pg[base + 1024] + Pg[base + cs + 1024] + bihh[j + 1024];
  const float gg = Pg[base + 2048] + Pg[base + cs + 2048] + bihh[j + 2048];
  const float og = Pg[base + 3072] + Pg[base + cs + 3072] + bihh[j + 3072];
  const float cn = sigmoidf_(fg) * c[id] + sigmoidf_(ig) * tanhf(gg);
  const float hn = sigmoidf_(og) * tanhf(cn);
  c[id] = cn;
  h[id] = hn;
  __bf16 hh, hl;
  split1(hn, hh, hl);
  hcat_h[(size_t)b * 2048 + j] = hh;
  hcat_l[(size_t)b * 2048 + j] = hl;
}

// ---------------------------------------------------------------------------
// Single-pass attention. WG (b, half) covers 256 enc rows; each of the 8
// waves is an INDEPENDENT online-softmax unit over its own 32 rows:
// score from register-resident row, then ctx += e*row into a private LDS
// slice (no barriers in the loop). Energy = sum of 4 split-K partials + bias
// (fused reduce). Defer-max (THR=8). 8-way exact merge at the end.
// L3-residency partition: rows < L3ROWS loaded normally (147 MB stays
// L3-resident across the 6 steps); rows >= L3ROWS use nt (stream, no
// pollution). Branch is wave-uniform (L3ROWS is a multiple of 32).
// ---------------------------------------------------------------------------
__global__ __launch_bounds__(512) void attn_part(
    const float* __restrict__ Pe, const float* __restrict__ attn_b,
    const float* __restrict__ enc,
    float* __restrict__ pml, float* __restrict__ pcacc, float* __restrict__ scb)
{
  const int b = blockIdx.x >> 1, half = blockIdx.x & 1;
  const int base = half * 256;
  const int t = threadIdx.x, lane = t & 63, wv = t >> 6;
  __shared__ __align__(16) float ctxa[8][1024];  // 32 KB, one slice per wave
  __shared__ float wml[8][2];
  const float* encb = enc + (size_t)b * (SS * HH);

  // energy reduce: er = sum of 4 chunks + attn_b
  f32x4 er[4];
  {
    const f32x4* P4 = (const f32x4*)Pe;
    const f32x4* B4 = (const f32x4*)attn_b;
#pragma unroll
    for (int i = 0; i < 4; ++i) {
      const size_t idx = (size_t)b * 256 + lane + 64 * i;
      f32x4 v = P4[idx];
      const f32x4 v1 = P4[idx + 65536], v2 = P4[idx + 131072], v3 = P4[idx + 196608];
      const f32x4 bb = B4[lane + 64 * i];
      v.x += v1.x + v2.x + v3.x + bb.x; v.y += v1.y + v2.y + v3.y + bb.y;
      v.z += v1.z + v2.z + v3.z + bb.z; v.w += v1.w + v2.w + v3.w + bb.w;
      er[i] = v;
    }
  }

  // zero this wave's ctx slice
  f32x4* cx = (f32x4*)ctxa[wv];
#pragma unroll
  for (int i = 0; i < 4; ++i) cx[lane + 64 * i] = f32x4{0.f, 0.f, 0.f, 0.f};

  float m = -INFINITY, lw = 0.0f;
  const int r0 = base + wv * 32;  // this wave's 32 rows
  const bool resident = (r0 < L3ROWS);  // uniform for the wave's whole range

  f32x4 r4[4];
  {
    const f32x4* row = (const f32x4*)(encb + (size_t)r0 * HH);
    if (resident) {
#pragma unroll
      for (int i = 0; i < 4; ++i) r4[i] = row[lane + 64 * i];
    } else {
#pragma unroll
      for (int i = 0; i < 4; ++i) r4[i] = __builtin_nontemporal_load(&row[lane + 64 * i]);
    }
  }

  for (int s = 0; s < 32; ++s) {
    f32x4 r4n[4];
    if (s + 1 < 32) {
      const f32x4* row = (const f32x4*)(encb + (size_t)(r0 + s + 1) * HH);
      if (resident) {
#pragma unroll
        for (int i = 0; i < 4; ++i) r4n[i] = row[lane + 64 * i];
      } else {
#pragma unroll
        for (int i = 0; i < 4; ++i) r4n[i] = __builtin_nontemporal_load(&row[lane + 64 * i]);
      }
    }
    float p = 0.0f;
#pragma unroll
    for (int i = 0; i < 4; ++i)
      p += r4[i].x * er[i].x + r4[i].y * er[i].y + r4[i].z * er[i].z + r4[i].w * er[i].w;
#pragma unroll
    for (int off = 32; off; off >>= 1) p += __shfl_xor(p, off);
    if (lane == 0) scb[(size_t)b * SS + r0 + s] = p;

    if (p > m + 8.0f) {  // defer-max rescale (wave-uniform; exact algebra)
      const float alpha = expf(m - p);  // first iter: exp(-inf)=0, ctx already 0
      lw *= alpha;
#pragma unroll
      for (int i = 0; i < 4; ++i) {
        f32x4 v = cx[lane + 64 * i];
        v.x *= alpha; v.y *= alpha; v.z *= alpha; v.w *= alpha;
        cx[lane + 64 * i] = v;
      }
      m = p;
    }
    const float e = expf(p - m);
    lw += e;
#pragma unroll
    for (int i = 0; i < 4; ++i) {
      f32x4 v = cx[lane + 64 * i];
      v.x += e * r4[i].x; v.y += e * r4[i].y; v.z += e * r4[i].z; v.w += e * r4[i].w;
      cx[lane + 64 * i] = v;
    }
#pragma unroll
    for (int i = 0; i < 4; ++i) r4[i] = r4n[i];
  }

  if (lane == 0) { wml[wv][0] = m; wml[wv][1] = lw; }
  __syncthreads();

  // 8-way merge (all threads)
  float M = -INFINITY;
#pragma unroll
  for (int w = 0; w < 8; ++w) M = fmaxf(M, wml[w][0]);
  float ew[8];
  float L = 0.0f;
#pragma unroll
  for (int w = 0; w < 8; ++w) { ew[w] = expf(wml[w][0] - M); L += wml[w][1] * ew[w]; }

  float2 acc = {0.0f, 0.0f};
#pragma unroll
  for (int w = 0; w < 8; ++w) {
    const float2 v = ((const float2*)ctxa[w])[t];
    acc.x += ew[w] * v.x; acc.y += ew[w] * v.y;
  }
  ((float2*)(pcacc + ((size_t)b * 2 + half) * HH))[t] = acc;
  if (t == 0) { pml[(b * 2 + half) * 2 + 0] = M; pml[(b * 2 + half) * 2 + 1] = L; }
}

// Merge the two halves: context -> hcat[:,1024:], weights -> wout.
__global__ __launch_bounds__(512) void attn_merge(
    const float* __restrict__ pml, const float* __restrict__ pcacc,
    const float* __restrict__ scb,
    __bf16* __restrict__ hcat_h, __bf16* __restrict__ hcat_l,
    float* __restrict__ wout)
{
  const int b = blockIdx.x, t = threadIdx.x;
  const float m0 = pml[b * 4 + 0], l0 = pml[b * 4 + 1];
  const float m1 = pml[b * 4 + 2], l1 = pml[b * 4 + 3];
  const float M = fmaxf(m0, m1);
  const float w0 = expf(m0 - M), w1 = expf(m1 - M);
  const float inv = 1.0f / (l0 * w0 + l1 * w1);
  const float2 c0 = ((const float2*)(pcacc + (size_t)b * 2048))[t];
  const float2 c1 = ((const float2*)(pcacc + (size_t)b * 2048 + 1024))[t];
  const float ox = (c0.x * w0 + c1.x * w1) * inv;
  const float oy = (c0.y * w0 + c1.y * w1) * inv;
  __bf16 h0, lo0, h1, lo1;
  split1(ox, h0, lo0); split1(oy, h1, lo1);
  const size_t ob = (size_t)b * 2048 + 1024 + 2 * t;
  *(bf16x2*)&hcat_h[ob] = bf16x2{h0, h1};
  *(bf16x2*)&hcat_l[ob] = bf16x2{lo0, lo1};
  wout[(size_t)b * SS + t] = expf(scb[(size_t)b * SS + t] - M) * inv;
}

// ---------------------------------------------------------------------------
// co reduce (4 chunks) + bias + tanh + split -> co_h/co_l.
// ---------------------------------------------------------------------------
__global__ __launch_bounds__(256) void co_reduce(
    const float* __restrict__ Pc, const float* __restrict__ concat_b,
    __bf16* __restrict__ co_h, __bf16* __restrict__ co_l)
{
  const int id = blockIdx.x * 256 + threadIdx.x;  // float4 group, 0..65535
  const size_t e4 = (size_t)id << 2;
  const int j = (int)(e4 & 1023);
  const size_t cs = (size_t)256 * 1024;
  float4 v = *(const float4*)(Pc + e4);
  const float4 v1 = *(const float4*)(Pc + e4 + cs);
  const float4 v2 = *(const float4*)(Pc + e4 + 2 * cs);
  const float4 v3 = *(const float4*)(Pc + e4 + 3 * cs);
  const float4 bb = *(const float4*)(concat_b + j);
  v.x = tanhf(v.x + v1.x + v2.x + v3.x + bb.x);
  v.y = tanhf(v.y + v1.y + v2.y + v3.y + bb.y);
  v.z = tanhf(v.z + v1.z + v2.z + v3.z + bb.z);
  v.w = tanhf(v.w + v1.w + v2.w + v3.w + bb.w);
  __bf16 h0, l0, h1, l1, h2, l2, h3, l3;
  split1(v.x, h0, l0); split1(v.y, h1, l1); split1(v.z, h2, l2); split1(v.w, h3, l3);
  *(bf16x4*)&co_h[e4] = bf16x4{h0, h1, h2, h3};
  *(bf16x4*)&co_l[e4] = bf16x4{l0, l1, l2, l3};
}

// ---------------------------------------------------------------------------
// logits reduce (2 chunks) + bias -> dec output, fused greedy argmax
// (first-index tie-break, deterministic).
// ---------------------------------------------------------------------------
__global__ __launch_bounds__(256) void argmax_reduce(
    const float* __restrict__ Pl, const float* __restrict__ lin_b,
    float* __restrict__ dec, int coff, int* __restrict__ inp)
{
  const int b = blockIdx.x, t = threadIdx.x;
  const size_t rb = (size_t)b * 2048;
  const size_t cs = (size_t)256 * 2048;
  float* drow = dec + (size_t)b * (NSTEPS * VV) + coff;
  float best = -INFINITY; int bi = 0;
  for (int j = t; j < VV; j += 256) {
    const float v = Pl[rb + j] + Pl[rb + cs + j] + lin_b[j];
    drow[j] = v;
    if (v > best) { best = v; bi = j; }
  }
  __shared__ float vs[256];
  __shared__ int   is[256];
  vs[t] = best; is[t] = bi;
  __syncthreads();
  for (int stp = 128; stp; stp >>= 1) {
    if (t < stp) {
      const float v2 = vs[t + stp]; const int i2 = is[t + stp];
      if (v2 > vs[t] || (v2 == vs[t] && i2 < is[t])) { vs[t] = v2; is[t] = i2; }
    }
    __syncthreads();
  }
  if (t == 0) inp[b] = is[0];
}

// ---------------------------------------------------------------------------
// Init: h,c <- h0,c0 ; h split into hcat[:,0:1024]; combined bias; SOS inp.
// ---------------------------------------------------------------------------
__global__ __launch_bounds__(256) void init_kernel(
    const float* __restrict__ h0, const float* __restrict__ c0,
    float* h, float* c,
    const float* __restrict__ b_ih, const float* __restrict__ b_hh,
    float* bihh, int* inp,
    __bf16* __restrict__ hcat_h, __bf16* __restrict__ hcat_l)
{
  const int id = blockIdx.x * 256 + threadIdx.x;
  if (id < BB * HH) {
    const float hv = h0[id];
    h[id] = hv;
    c[id] = c0[id];
    __bf16 hh, hl;
    split1(hv, hh, hl);
    const int b = id >> 10, j = id & 1023;
    hcat_h[(size_t)b * 2048 + j] = hh;
    hcat_l[(size_t)b * 2048 + j] = hl;
  }
  if (id < 4096) bihh[id] = b_ih[id] + b_hh[id];
  if (id < BB) inp[id] = SOS;
}

extern "C" void kernel_launch(void* const* d_in, const int* in_sizes, int n_in,
                              void* d_out, int out_size, void* d_ws, size_t ws_size,
                              hipStream_t stream)
{
  (void)in_sizes; (void)n_in; (void)out_size; (void)ws_size;
  const float* enc      = (const float*)d_in[0];
  const float* h0       = (const float*)d_in[1];
  const float* c0       = (const float*)d_in[2];
  const float* emb      = (const float*)d_in[3];
  const float* W_ih     = (const float*)d_in[4];
  const float* W_hh     = (const float*)d_in[5];
  const float* b_ih     = (const float*)d_in[6];
  const float* b_hh     = (const float*)d_in[7];
  const float* attn_W   = (const float*)d_in[8];
  const float* attn_b   = (const float*)d_in[9];
  const float* concat_W = (const float*)d_in[10];
  const float* concat_b = (const float*)d_in[11];
  const float* lin_W    = (const float*)d_in[12];
  const float* lin_b    = (const float*)d_in[13];

  float* out = (float*)d_out;
  float* dec = out;                                  // [256][6][2048]
  float* h   = out + (size_t)BB * NSTEPS * VV;       // [256][1024]
  float* c   = h + (size_t)BB * HH;                  // [256][1024]
  float* wts = c + (size_t)BB * HH;                  // [256][512]

  char* w = (char*)d_ws;
  auto alloc = [&](size_t bytes) { char* p = w; w += (bytes + 255) & ~255ull; return p; };
  float*  bihh    = (float*)alloc(4096 * 4);
  int*    inp     = (int*)alloc(BB * 4);
  __bf16* Wcat_h  = (__bf16*)alloc((size_t)4096 * 2048 * 2);
  __bf16* Wcat_l  = (__bf16*)alloc((size_t)4096 * 2048 * 2);
  __bf16* attnW_h = (__bf16*)alloc((size_t)1024 * 1024 * 2);
  __bf16* attnW_l = (__bf16*)alloc((size_t)1024 * 1024 * 2);
  __bf16* catW_h  = (__bf16*)alloc((size_t)1024 * 2048 * 2);
  __bf16* catW_l  = (__bf16*)alloc((size_t)1024 * 2048 * 2);
  __bf16* linW_h  = (__bf16*)alloc((size_t)2048 * 1024 * 2);
  __bf16* linW_l  = (__bf16*)alloc((size_t)2048 * 1024 * 2);
  __bf16* emb_h   = (__bf16*)alloc((size_t)VV * HH * 2);
  __bf16* emb_l   = (__bf16*)alloc((size_t)VV * HH * 2);
  __bf16* hcat_h  = (__bf16*)alloc((size_t)BB * 2048 * 2);
  __bf16* hcat_l  = (__bf16*)alloc((size_t)BB * 2048 * 2);
  __bf16* co_h    = (__bf16*)alloc((size_t)BB * 1024 * 2);
  __bf16* co_l    = (__bf16*)alloc((size_t)BB * 1024 * 2);
  float*  pml     = (float*)alloc(BB * 4 * 4);
  float*  pcacc   = (float*)alloc((size_t)BB * 2 * HH * 4);
  float*  scb     = (float*)alloc((size_t)BB * SS * 4);
  float*  Pg      = (float*)alloc((size_t)2 * BB * 4096 * 4);  // gates partials
  float*  Pe      = (float*)alloc((size_t)4 * BB * 1024 * 4);  // energy partials
  float*  Pc      = (float*)alloc((size_t)4 * BB * 1024 * 4);  // concat partials
  float*  Pl      = (float*)alloc((size_t)2 * BB * 2048 * 4);  // logits partials

  conv_all<<<15360, 256, 0, stream>>>(W_ih, W_hh, attn_W, concat_W, lin_W, emb,
                                      Wcat_h, Wcat_l, attnW_h, attnW_l,
                                      catW_h, catW_l, linW_h, linW_l, emb_h, emb_l);
  init_kernel<<<1024, 256, 0, stream>>>(h0, c0, h, c, b_ih, b_hh, bihh, inp,
                                        hcat_h, hcat_l);

  for (int step = 0; step < NSTEPS; ++step) {
    // gates partials: [emb[inp]|h] @ Wcat^T, split-K2 (1024 each), XCD-chunked
    gemm3<1><<<512, 256, 0, stream>>>(
        emb_h, emb_l, HH, hcat_h, hcat_l, inp, Wcat_h, Wcat_l, 2048,
        1024, Pg, 4096, 4, 2);
    lstm_reduce<<<1024, 256, 0, stream>>>(Pg, bihh, c, h, hcat_h, hcat_l);
    // energy partials: h @ attn_W^T, split-K4 (256 each)
    gemm3<0><<<256, 256, 0, stream>>>(
        hcat_h, hcat_l, 2048, nullptr, nullptr, nullptr, attnW_h, attnW_l, 1024,
        256, Pe, 1024, 4, 4);
    // fused energy-reduce + single-pass flash attention (L3-partitioned enc)
    attn_part<<<2 * BB, 512, 0, stream>>>(Pe, attn_b, enc, pml, pcacc, scb);
    attn_merge<<<BB, 512, 0, stream>>>(pml, pcacc, scb, hcat_h, hcat_l, wts);
    // concat partials: [h|ctx] @ concat_W^T, split-K4 (512 each)
    gemm3<0><<<256, 256, 0, stream>>>(
        hcat_h, hcat_l, 2048, nullptr, nullptr, nullptr, catW_h, catW_l, 2048,
        512, Pc, 1024, 4, 4);
    co_reduce<<<256, 256, 0, stream>>>(Pc, concat_b, co_h, co_l);
    // logits partials: co @ lin_W^T, split-K2 (512 each)
    gemm3<0><<<256, 256, 0, stream>>>(
        co_h, co_l, 1024, nullptr, nullptr, nullptr, linW_h, linW_l, 1024,
        512, Pl, 2048, 4, 2);
    argmax_reduce<<<BB, 256, 0, stream>>>(Pl, lin_b, dec, step * VV, inp);
  }
}

// Round 8
// 956.026 us; speedup vs baseline: 1.1488x; 1.1488x over previous
//
#include <hip/hip_runtime.h>
#include <math.h>

#define HH 1024
#define VV 2048
#define BB 256
#define SS 512
#define NSTEPS 6
#define SOS 129

typedef __attribute__((ext_vector_type(8))) __bf16 bf16x8;
typedef __attribute__((ext_vector_type(4))) __bf16 bf16x4;
typedef __attribute__((ext_vector_type(2))) __bf16 bf16x2;
typedef __attribute__((ext_vector_type(4))) float f32x4;

__device__ __forceinline__ float sigmoidf_(float x) { return 1.0f / (1.0f + expf(-x)); }

__device__ __forceinline__ void split1(float x, __bf16& h, __bf16& l) {
  h = (__bf16)x;
  l = (__bf16)(x - (float)h);
}

// async global->LDS, 16B per lane; LDS dest must be wave-uniform base.
__device__ __forceinline__ void gll16(const __bf16* src, __bf16* ldst) {
  __builtin_amdgcn_global_load_lds(
      (const __attribute__((address_space(1))) unsigned*)(const void*)src,
      (__attribute__((address_space(3))) unsigned*)(void*)ldst, 16, 0, 0);
}

// ---------------------------------------------------------------------------
// Split-bf16 MFMA GEMM, double-buffered, global_load_lds staging.
// Tile 64x64, BK=64, 256 threads (4 waves), wave-tile 32x32. XCD-chunked
// 1-D grid decode (x-major: all y,z of one x-tile share an XCD).
// OMODE 0: split-K fp32 partial store  P[z][m][n].
// OMODE 1: full-K, epilogue tanh(acc+bias) -> split bf16 (Ch,Cl), nz==1.
// ---------------------------------------------------------------------------
template<int OMODE>
__global__ __launch_bounds__(256) void gemm3(
    const __bf16* __restrict__ Ah, const __bf16* __restrict__ Al, int lda,
    const __bf16* __restrict__ Bh, const __bf16* __restrict__ Bl, int K,
    int kLen, float* __restrict__ P, int ldc,
    int ny, int nz,
    const float* __restrict__ bias,
    __bf16* __restrict__ Ch, __bf16* __restrict__ Cl)
{
  __shared__ __align__(16) __bf16 lds[2][4][64 * 64];  // 64 KB
  const int t = threadIdx.x, lane = t & 63, wv = t >> 6;

  const int chunk = (int)(gridDim.x >> 3);
  const int w = (blockIdx.x & 7) * chunk + (blockIdx.x >> 3);
  const int bz = w % nz;
  const int by = (w / nz) % ny;
  const int bx = w / (nz * ny);
  const int row0 = by * 64, col0 = bx * 64;

  const int sslot = lane & 7;
  const int srw   = lane >> 3;
  int sw[2];
  const __bf16 *arh[2], *arl[2], *brh[2], *brl[2];
#pragma unroll
  for (int hf = 0; hf < 2; ++hf) {
    const int tr = wv * 16 + hf * 8 + srw;
    sw[hf] = (sslot ^ (tr & 7)) << 3;
    const int ar = row0 + tr;
    arh[hf] = Ah + (size_t)ar * lda;
    arl[hf] = Al + (size_t)ar * lda;
    const int br = col0 + tr;
    brh[hf] = Bh + (size_t)br * K;
    brl[hf] = Bl + (size_t)br * K;
  }

  const int wr = (wv >> 1) * 32, wc = (wv & 1) * 32;
  const int fr = lane & 15, kb = (lane >> 4) * 8;

  const f32x4 fz = {0.f, 0.f, 0.f, 0.f};
  f32x4 acc[2][2] = {{fz, fz}, {fz, fz}};

  const int tBeg = (bz * kLen) >> 6;
  const int nt = kLen >> 6;

  auto stage = [&](int tIdx, int bi) {
    const int k0 = tIdx << 6;
#pragma unroll
    for (int hf = 0; hf < 2; ++hf) {
      const int rb = (wv * 16 + hf * 8) * 64;
      gll16(arh[hf] + k0 + sw[hf], &lds[bi][0][rb]);
      gll16(arl[hf] + k0 + sw[hf], &lds[bi][1][rb]);
      gll16(brh[hf] + k0 + sw[hf], &lds[bi][2][rb]);
      gll16(brl[hf] + k0 + sw[hf], &lds[bi][3][rb]);
    }
  };

  auto compute = [&](int bi) {
#pragma unroll
    for (int kc = 0; kc < 2; ++kc) {
      const int e = kc * 32 + kb;
      bf16x8 a_h[2], a_l[2], b_h[2], b_l[2];
#pragma unroll
      for (int i = 0; i < 2; ++i) {
        const int ra = wr + i * 16 + fr;
        const int ia = ra * 64 + (e ^ ((ra & 7) << 3));
        a_h[i] = *(const bf16x8*)&lds[bi][0][ia];
        a_l[i] = *(const bf16x8*)&lds[bi][1][ia];
        const int rb2 = wc + i * 16 + fr;
        const int ib = rb2 * 64 + (e ^ ((rb2 & 7) << 3));
        b_h[i] = *(const bf16x8*)&lds[bi][2][ib];
        b_l[i] = *(const bf16x8*)&lds[bi][3][ib];
      }
#pragma unroll
      for (int i = 0; i < 2; ++i)
#pragma unroll
        for (int j = 0; j < 2; ++j)
          acc[i][j] = __builtin_amdgcn_mfma_f32_16x16x32_bf16(a_h[i], b_h[j], acc[i][j], 0, 0, 0);
#pragma unroll
      for (int i = 0; i < 2; ++i)
#pragma unroll
        for (int j = 0; j < 2; ++j)
          acc[i][j] = __builtin_amdgcn_mfma_f32_16x16x32_bf16(a_h[i], b_l[j], acc[i][j], 0, 0, 0);
#pragma unroll
      for (int i = 0; i < 2; ++i)
#pragma unroll
        for (int j = 0; j < 2; ++j)
          acc[i][j] = __builtin_amdgcn_mfma_f32_16x16x32_bf16(a_l[i], b_h[j], acc[i][j], 0, 0, 0);
    }
  };

  stage(tBeg, 0);
  __syncthreads();
  int cur = 0;
  for (int tk = 0; tk < nt; ++tk) {
    if (tk + 1 < nt) stage(tBeg + tk + 1, cur ^ 1);
    compute(cur);
    __syncthreads();
    cur ^= 1;
  }

  if (OMODE == 0) {
    float* Cp = P + (size_t)bz * 256 * ldc;
#pragma unroll
    for (int i = 0; i < 2; ++i)
#pragma unroll
      for (int j = 0; j < 2; ++j) {
        const int col = col0 + wc + j * 16 + fr;
#pragma unroll
        for (int r = 0; r < 4; ++r) {
          const int row = row0 + wr + i * 16 + (lane >> 4) * 4 + r;
          Cp[(size_t)row * ldc + col] = acc[i][j][r];
        }
      }
  } else {
#pragma unroll
    for (int i = 0; i < 2; ++i)
#pragma unroll
      for (int j = 0; j < 2; ++j) {
        const int col = col0 + wc + j * 16 + fr;
        const float bb = bias[col];
#pragma unroll
        for (int r = 0; r < 4; ++r) {
          const int row = row0 + wr + i * 16 + (lane >> 4) * 4 + r;
          const float v = tanhf(acc[i][j][r] + bb);
          __bf16 vh, vl;
          split1(v, vh, vl);
          Ch[(size_t)row * ldc + col] = vh;
          Cl[(size_t)row * ldc + col] = vl;
        }
      }
  }
}

// ---------------------------------------------------------------------------
// Fused gates GEMM (full K=2048) + LSTM pointwise. Gate columns are
// INTERLEAVED at conversion time (col r' = 4*j + gate, gate in {i,f,g,o}),
// so one 64-col tile = 16 units x 4 gates and the epilogue can do the LSTM
// entirely in-block: acc tile + bias -> LDS scratch -> c/h update -> split-h
// written to the CURRENT hcat buffer (h-part). A = [emb[inp[r]] | hprev].
// ---------------------------------------------------------------------------
__global__ __launch_bounds__(256) void gates_lstm(
    const __bf16* __restrict__ emb_h, const __bf16* __restrict__ emb_l,
    const __bf16* __restrict__ hprev_h, const __bf16* __restrict__ hprev_l,
    const int* __restrict__ aidx,
    const __bf16* __restrict__ Bh, const __bf16* __restrict__ Bl,  // [4096][2048]
    const float* __restrict__ bihh,                                // interleaved
    float* __restrict__ c, float* __restrict__ h,
    __bf16* __restrict__ hcur_h, __bf16* __restrict__ hcur_l)
{
  __shared__ __align__(16) __bf16 lds[2][4][64 * 64];  // 64 KB
  const int t = threadIdx.x, lane = t & 63, wv = t >> 6;

  const int chunk = (int)(gridDim.x >> 3);          // 256 -> 32
  const int w = (blockIdx.x & 7) * chunk + (blockIdx.x >> 3);
  const int by = w & 3;                             // ny=4, nz=1, x-major
  const int bx = w >> 2;
  const int row0 = by * 64, col0 = bx * 64;

  const int sslot = lane & 7;
  const int srw   = lane >> 3;
  int sw[2];
  const __bf16 *arh[2], *arl[2], *a1h[2], *a1l[2], *brh[2], *brl[2];
#pragma unroll
  for (int hf = 0; hf < 2; ++hf) {
    const int tr = wv * 16 + hf * 8 + srw;
    sw[hf] = (sslot ^ (tr & 7)) << 3;
    const int ar = row0 + tr;
    const int r = aidx[ar];
    arh[hf] = emb_h + (size_t)r * HH;
    arl[hf] = emb_l + (size_t)r * HH;
    a1h[hf] = hprev_h + (size_t)ar * 2048;
    a1l[hf] = hprev_l + (size_t)ar * 2048;
    const int br = col0 + tr;
    brh[hf] = Bh + (size_t)br * 2048;
    brl[hf] = Bl + (size_t)br * 2048;
  }

  const int wr = (wv >> 1) * 32, wc = (wv & 1) * 32;
  const int fr = lane & 15, kb = (lane >> 4) * 8;

  const f32x4 fz = {0.f, 0.f, 0.f, 0.f};
  f32x4 acc[2][2] = {{fz, fz}, {fz, fz}};

  auto stage = [&](int tIdx, int bi) {
    const int k0 = tIdx << 6;
#pragma unroll
    for (int hf = 0; hf < 2; ++hf) {
      const int rb = (wv * 16 + hf * 8) * 64;
      const __bf16 *sa_h, *sa_l;
      if (k0 >= HH) {
        sa_h = a1h[hf] + (k0 - HH) + sw[hf];
        sa_l = a1l[hf] + (k0 - HH) + sw[hf];
      } else {
        sa_h = arh[hf] + k0 + sw[hf];
        sa_l = arl[hf] + k0 + sw[hf];
      }
      gll16(sa_h, &lds[bi][0][rb]);
      gll16(sa_l, &lds[bi][1][rb]);
      gll16(brh[hf] + k0 + sw[hf], &lds[bi][2][rb]);
      gll16(brl[hf] + k0 + sw[hf], &lds[bi][3][rb]);
    }
  };

  auto compute = [&](int bi) {
#pragma unroll
    for (int kc = 0; kc < 2; ++kc) {
      const int e = kc * 32 + kb;
      bf16x8 a_h[2], a_l[2], b_h[2], b_l[2];
#pragma unroll
      for (int i = 0; i < 2; ++i) {
        const int ra = wr + i * 16 + fr;
        const int ia = ra * 64 + (e ^ ((ra & 7) << 3));
        a_h[i] = *(const bf16x8*)&lds[bi][0][ia];
        a_l[i] = *(const bf16x8*)&lds[bi][1][ia];
        const int rb2 = wc + i * 16 + fr;
        const int ib = rb2 * 64 + (e ^ ((rb2 & 7) << 3));
        b_h[i] = *(const bf16x8*)&lds[bi][2][ib];
        b_l[i] = *(const bf16x8*)&lds[bi][3][ib];
      }
#pragma unroll
      for (int i = 0; i < 2; ++i)
#pragma unroll
        for (int j = 0; j < 2; ++j)
          acc[i][j] = __builtin_amdgcn_mfma_f32_16x16x32_bf16(a_h[i], b_h[j], acc[i][j], 0, 0, 0);
#pragma unroll
      for (int i = 0; i < 2; ++i)
#pragma unroll
        for (int j = 0; j < 2; ++j)
          acc[i][j] = __builtin_amdgcn_mfma_f32_16x16x32_bf16(a_h[i], b_l[j], acc[i][j], 0, 0, 0);
#pragma unroll
      for (int i = 0; i < 2; ++i)
#pragma unroll
        for (int j = 0; j < 2; ++j)
          acc[i][j] = __builtin_amdgcn_mfma_f32_16x16x32_bf16(a_l[i], b_h[j], acc[i][j], 0, 0, 0);
    }
  };

  stage(0, 0);
  __syncthreads();
  int cur = 0;
  for (int tk = 0; tk < 32; ++tk) {
    if (tk + 1 < 32) stage(tk + 1, cur ^ 1);
    compute(cur);
    __syncthreads();
    cur ^= 1;
  }

  // ---- LSTM epilogue: acc + bias -> LDS fp32 scratch [64][68] (reuses
  // the now-dead staging LDS), then pointwise update.
  float (*sc)[68] = (float (*)[68])(&lds[0][0][0]);  // 17.4 KB < 32 KB region
#pragma unroll
  for (int i = 0; i < 2; ++i)
#pragma unroll
    for (int j = 0; j < 2; ++j) {
      const int cl = wc + j * 16 + fr;
      const float bb = bihh[col0 + cl];
#pragma unroll
      for (int r = 0; r < 4; ++r) {
        const int rl = wr + i * 16 + (lane >> 4) * 4 + r;
        sc[rl][cl] = acc[i][j][r] + bb;
      }
    }
  __syncthreads();

  const int rl2 = t >> 2;              // local row 0..63
  const int b2 = row0 + rl2;           // batch row
  const int u0 = (t & 3) << 2;         // first of 4 units
  const int j0 = (col0 >> 2) + u0;     // global unit index
  const float4 cv = *(const float4*)&c[b2 * 1024 + j0];
  float cn[4], hn[4];
#pragma unroll
  for (int q = 0; q < 4; ++q) {
    const int u = u0 + q;
    const float ig = sc[rl2][u * 4 + 0];
    const float fg = sc[rl2][u * 4 + 1];
    const float gg = sc[rl2][u * 4 + 2];
    const float og = sc[rl2][u * 4 + 3];
    const float cold = (&cv.x)[q];
    cn[q] = sigmoidf_(fg) * cold + sigmoidf_(ig) * tanhf(gg);
    hn[q] = sigmoidf_(og) * tanhf(cn[q]);
  }
  *(float4*)&c[b2 * 1024 + j0] = float4{cn[0], cn[1], cn[2], cn[3]};
  *(float4*)&h[b2 * 1024 + j0] = float4{hn[0], hn[1], hn[2], hn[3]};
  __bf16 hh[4], hl[4];
#pragma unroll
  for (int q = 0; q < 4; ++q) split1(hn[q], hh[q], hl[q]);
  *(bf16x4*)&hcur_h[(size_t)b2 * 2048 + j0] = bf16x4{hh[0], hh[1], hh[2], hh[3]};
  *(bf16x4*)&hcur_l[(size_t)b2 * 2048 + j0] = bf16x4{hl[0], hl[1], hl[2], hl[3]};
}

// ---------------------------------------------------------------------------
// One-shot conversion of all fp32 weights (+ embedding) to split hi/lo bf16.
// Wcat rows are INTERLEAVED: dest row r' = 4*(r&1023) + (r>>10).
// ---------------------------------------------------------------------------
__global__ __launch_bounds__(256) void conv_all(
    const float* __restrict__ W_ih, const float* __restrict__ W_hh,
    const float* __restrict__ attn_W, const float* __restrict__ concat_W,
    const float* __restrict__ lin_W, const float* __restrict__ emb,
    __bf16* __restrict__ Wcat_h, __bf16* __restrict__ Wcat_l,
    __bf16* __restrict__ attnW_h, __bf16* __restrict__ attnW_l,
    __bf16* __restrict__ catW_h, __bf16* __restrict__ catW_l,
    __bf16* __restrict__ linW_h, __bf16* __restrict__ linW_l,
    __bf16* __restrict__ emb_h, __bf16* __restrict__ emb_l)
{
  const int i = blockIdx.x * 256 + threadIdx.x;
  const float* s;
  __bf16 *dh, *dl;
  size_t so, dofs;
  if (i < 2097152) {
    const int ii = i & 1048575;
    const int r = ii >> 8, cp = (ii & 255) << 2;
    s = (i < 1048576) ? W_ih : W_hh;
    so = (size_t)r * 1024 + cp;
    dh = Wcat_h; dl = Wcat_l;
    const int rr = ((r & 1023) << 2) | (r >> 10);   // gate interleave
    dofs = (size_t)rr * 2048 + ((i < 1048576) ? 0 : 1024) + cp;
  } else if (i < 2359296) {
    const size_t ii = (size_t)(i - 2097152) << 2;
    s = attn_W; so = ii; dh = attnW_h; dl = attnW_l; dofs = ii;
  } else if (i < 2883584) {
    const size_t ii = (size_t)(i - 2359296) << 2;
    s = concat_W; so = ii; dh = catW_h; dl = catW_l; dofs = ii;
  } else if (i < 3407872) {
    const size_t ii = (size_t)(i - 2883584) << 2;
    s = lin_W; so = ii; dh = linW_h; dl = linW_l; dofs = ii;
  } else {
    const size_t ii = (size_t)(i - 3407872) << 2;
    s = emb; so = ii; dh = emb_h; dl = emb_l; dofs = ii;
  }
  const float4 v = *(const float4*)(s + so);
  __bf16 h0, l0, h1, l1, h2, l2, h3, l3;
  split1(v.x, h0, l0); split1(v.y, h1, l1); split1(v.z, h2, l2); split1(v.w, h3, l3);
  *(bf16x4*)&dh[dofs] = bf16x4{h0, h1, h2, h3};
  *(bf16x4*)&dl[dofs] = bf16x4{l0, l1, l2, l3};
}

// ---------------------------------------------------------------------------
// Single-pass attention, ONE WG per batch row (8 waves x 64 enc rows each),
// fused energy-reduce at entry and fused 8-way merge + output at exit.
// Scores kept in LDS; weights written directly. All enc loads non-temporal
// (R7 lesson: enc is a pure stream; cached-load partition regressed 25%).
// ---------------------------------------------------------------------------
__global__ __launch_bounds__(512) void attn_fused(
    const float* __restrict__ Pe, const float* __restrict__ attn_b,
    const float* __restrict__ enc,
    __bf16* __restrict__ hcur_h, __bf16* __restrict__ hcur_l,
    float* __restrict__ wout)
{
  const int b = blockIdx.x;
  const int t = threadIdx.x, lane = t & 63, wv = t >> 6;
  __shared__ __align__(16) float ctxa[8][1024];  // 32 KB
  __shared__ float scl[SS];
  __shared__ float wml[8][2];
  const float* encb = enc + (size_t)b * (SS * HH);

  // energy reduce: er = sum of 4 split-K chunks + attn_b
  f32x4 er[4];
  {
    const f32x4* P4 = (const f32x4*)Pe;
    const f32x4* B4 = (const f32x4*)attn_b;
#pragma unroll
    for (int i = 0; i < 4; ++i) {
      const size_t idx = (size_t)b * 256 + lane + 64 * i;
      f32x4 v = P4[idx];
      const f32x4 v1 = P4[idx + 65536], v2 = P4[idx + 131072], v3 = P4[idx + 196608];
      const f32x4 bb = B4[lane + 64 * i];
      v.x += v1.x + v2.x + v3.x + bb.x; v.y += v1.y + v2.y + v3.y + bb.y;
      v.z += v1.z + v2.z + v3.z + bb.z; v.w += v1.w + v2.w + v3.w + bb.w;
      er[i] = v;
    }
  }

  f32x4* cx = (f32x4*)ctxa[wv];
#pragma unroll
  for (int i = 0; i < 4; ++i) cx[lane + 64 * i] = f32x4{0.f, 0.f, 0.f, 0.f};

  float m = -INFINITY, lw = 0.0f;
  const int r0 = wv * 64;  // this wave's 64 rows

  f32x4 r4[4];
  {
    const f32x4* row = (const f32x4*)(encb + (size_t)r0 * HH);
#pragma unroll
    for (int i = 0; i < 4; ++i) r4[i] = __builtin_nontemporal_load(&row[lane + 64 * i]);
  }

  for (int s = 0; s < 64; ++s) {
    f32x4 r4n[4];
    if (s + 1 < 64) {
      const f32x4* row = (const f32x4*)(encb + (size_t)(r0 + s + 1) * HH);
#pragma unroll
      for (int i = 0; i < 4; ++i) r4n[i] = __builtin_nontemporal_load(&row[lane + 64 * i]);
    }
    float p = 0.0f;
#pragma unroll
    for (int i = 0; i < 4; ++i)
      p += r4[i].x * er[i].x + r4[i].y * er[i].y + r4[i].z * er[i].z + r4[i].w * er[i].w;
#pragma unroll
    for (int off = 32; off; off >>= 1) p += __shfl_xor(p, off);
    if (lane == 0) scl[r0 + s] = p;

    if (p > m + 8.0f) {  // defer-max rescale (wave-uniform; exact algebra)
      const float alpha = expf(m - p);
      lw *= alpha;
#pragma unroll
      for (int i = 0; i < 4; ++i) {
        f32x4 v = cx[lane + 64 * i];
        v.x *= alpha; v.y *= alpha; v.z *= alpha; v.w *= alpha;
        cx[lane + 64 * i] = v;
      }
      m = p;
    }
    const float e = expf(p - m);
    lw += e;
#pragma unroll
    for (int i = 0; i < 4; ++i) {
      f32x4 v = cx[lane + 64 * i];
      v.x += e * r4[i].x; v.y += e * r4[i].y; v.z += e * r4[i].z; v.w += e * r4[i].w;
      cx[lane + 64 * i] = v;
    }
#pragma unroll
    for (int i = 0; i < 4; ++i) r4[i] = r4n[i];
  }

  if (lane == 0) { wml[wv][0] = m; wml[wv][1] = lw; }
  __syncthreads();

  // 8-way exact merge (all 512 threads)
  float M = -INFINITY;
#pragma unroll
  for (int w = 0; w < 8; ++w) M = fmaxf(M, wml[w][0]);
  float ew[8];
  float L = 0.0f;
#pragma unroll
  for (int w = 0; w < 8; ++w) { ew[w] = expf(wml[w][0] - M); L += wml[w][1] * ew[w]; }
  const float inv = 1.0f / L;

  float2 acc = {0.0f, 0.0f};
#pragma unroll
  for (int w = 0; w < 8; ++w) {
    const float2 v = ((const float2*)ctxa[w])[t];
    acc.x += ew[w] * v.x; acc.y += ew[w] * v.y;
  }
  const float ox = acc.x * inv, oy = acc.y * inv;
  __bf16 h0b, lo0, h1b, lo1;
  split1(ox, h0b, lo0); split1(oy, h1b, lo1);
  const size_t ob = (size_t)b * 2048 + 1024 + 2 * t;
  *(bf16x2*)&hcur_h[ob] = bf16x2{h0b, h1b};
  *(bf16x2*)&hcur_l[ob] = bf16x2{lo0, lo1};
  wout[(size_t)b * SS + t] = expf(scl[t] - M) * inv;
}

// ---------------------------------------------------------------------------
// logits reduce (2 chunks) + bias -> dec output, fused greedy argmax.
// ---------------------------------------------------------------------------
__global__ __launch_bounds__(256) void argmax_reduce(
    const float* __restrict__ Pl, const float* __restrict__ lin_b,
    float* __restrict__ dec, int coff, int* __restrict__ inp)
{
  const int b = blockIdx.x, t = threadIdx.x;
  const size_t rb = (size_t)b * 2048;
  const size_t cs = (size_t)256 * 2048;
  float* drow = dec + (size_t)b * (NSTEPS * VV) + coff;
  float best = -INFINITY; int bi = 0;
  for (int j = t; j < VV; j += 256) {
    const float v = Pl[rb + j] + Pl[rb + cs + j] + lin_b[j];
    drow[j] = v;
    if (v > best) { best = v; bi = j; }
  }
  __shared__ float vs[256];
  __shared__ int   is[256];
  vs[t] = best; is[t] = bi;
  __syncthreads();
  for (int stp = 128; stp; stp >>= 1) {
    if (t < stp) {
      const float v2 = vs[t + stp]; const int i2 = is[t + stp];
      if (v2 > vs[t] || (v2 == vs[t] && i2 < is[t])) { vs[t] = v2; is[t] = i2; }
    }
    __syncthreads();
  }
  if (t == 0) inp[b] = is[0];
}

// ---------------------------------------------------------------------------
// Init: h,c <- h0,c0 ; h0 split into hcatA h-part; interleaved bias; SOS inp.
// ---------------------------------------------------------------------------
__global__ __launch_bounds__(256) void init_kernel(
    const float* __restrict__ h0, const float* __restrict__ c0,
    float* h, float* c,
    const float* __restrict__ b_ih, const float* __restrict__ b_hh,
    float* bihh, int* inp,
    __bf16* __restrict__ hprev_h, __bf16* __restrict__ hprev_l)
{
  const int id = blockIdx.x * 256 + threadIdx.x;
  if (id < BB * HH) {
    const float hv = h0[id];
    h[id] = hv;
    c[id] = c0[id];
    __bf16 hh, hl;
    split1(hv, hh, hl);
    const int b = id >> 10, j = id & 1023;
    hprev_h[(size_t)b * 2048 + j] = hh;
    hprev_l[(size_t)b * 2048 + j] = hl;
  }
  if (id < 4096) bihh[((id & 1023) << 2) | (id >> 10)] = b_ih[id] + b_hh[id];
  if (id < BB) inp[id] = SOS;
}

extern "C" void kernel_launch(void* const* d_in, const int* in_sizes, int n_in,
                              void* d_out, int out_size, void* d_ws, size_t ws_size,
                              hipStream_t stream)
{
  (void)in_sizes; (void)n_in; (void)out_size; (void)ws_size;
  const float* enc      = (const float*)d_in[0];
  const float* h0       = (const float*)d_in[1];
  const float* c0       = (const float*)d_in[2];
  const float* emb      = (const float*)d_in[3];
  const float* W_ih     = (const float*)d_in[4];
  const float* W_hh     = (const float*)d_in[5];
  const float* b_ih     = (const float*)d_in[6];
  const float* b_hh     = (const float*)d_in[7];
  const float* attn_W   = (const float*)d_in[8];
  const float* attn_b   = (const float*)d_in[9];
  const float* concat_W = (const float*)d_in[10];
  const float* concat_b = (const float*)d_in[11];
  const float* lin_W    = (const float*)d_in[12];
  const float* lin_b    = (const float*)d_in[13];

  float* out = (float*)d_out;
  float* dec = out;                                  // [256][6][2048]
  float* h   = out + (size_t)BB * NSTEPS * VV;       // [256][1024]
  float* c   = h + (size_t)BB * HH;                  // [256][1024]
  float* wts = c + (size_t)BB * HH;                  // [256][512]

  char* w = (char*)d_ws;
  auto alloc = [&](size_t bytes) { char* p = w; w += (bytes + 255) & ~255ull; return p; };
  float*  bihh    = (float*)alloc(4096 * 4);
  int*    inp     = (int*)alloc(BB * 4);
  __bf16* Wcat_h  = (__bf16*)alloc((size_t)4096 * 2048 * 2);
  __bf16* Wcat_l  = (__bf16*)alloc((size_t)4096 * 2048 * 2);
  __bf16* attnW_h = (__bf16*)alloc((size_t)1024 * 1024 * 2);
  __bf16* attnW_l = (__bf16*)alloc((size_t)1024 * 1024 * 2);
  __bf16* catW_h  = (__bf16*)alloc((size_t)1024 * 2048 * 2);
  __bf16* catW_l  = (__bf16*)alloc((size_t)1024 * 2048 * 2);
  __bf16* linW_h  = (__bf16*)alloc((size_t)2048 * 1024 * 2);
  __bf16* linW_l  = (__bf16*)alloc((size_t)2048 * 1024 * 2);
  __bf16* emb_h   = (__bf16*)alloc((size_t)VV * HH * 2);
  __bf16* emb_l   = (__bf16*)alloc((size_t)VV * HH * 2);
  __bf16* hcatA_h = (__bf16*)alloc((size_t)BB * 2048 * 2);
  __bf16* hcatA_l = (__bf16*)alloc((size_t)BB * 2048 * 2);
  __bf16* hcatB_h = (__bf16*)alloc((size_t)BB * 2048 * 2);
  __bf16* hcatB_l = (__bf16*)alloc((size_t)BB * 2048 * 2);
  __bf16* co_h    = (__bf16*)alloc((size_t)BB * 1024 * 2);
  __bf16* co_l    = (__bf16*)alloc((size_t)BB * 1024 * 2);
  float*  Pe      = (float*)alloc((size_t)4 * BB * 1024 * 4);  // energy partials
  float*  Pl      = (float*)alloc((size_t)2 * BB * 2048 * 4);  // logits partials

  conv_all<<<15360, 256, 0, stream>>>(W_ih, W_hh, attn_W, concat_W, lin_W, emb,
                                      Wcat_h, Wcat_l, attnW_h, attnW_l,
                                      catW_h, catW_l, linW_h, linW_l, emb_h, emb_l);
  init_kernel<<<1024, 256, 0, stream>>>(h0, c0, h, c, b_ih, b_hh, bihh, inp,
                                        hcatA_h, hcatA_l);

  for (int step = 0; step < NSTEPS; ++step) {
    __bf16* hprev_h = (step & 1) ? hcatB_h : hcatA_h;
    __bf16* hprev_l = (step & 1) ? hcatB_l : hcatA_l;
    __bf16* hcur_h  = (step & 1) ? hcatA_h : hcatB_h;
    __bf16* hcur_l  = (step & 1) ? hcatA_l : hcatB_l;

    // gates GEMM (full K) + fused LSTM -> c, h, hcur[0:1024]
    gates_lstm<<<256, 256, 0, stream>>>(
        emb_h, emb_l, hprev_h, hprev_l, inp, Wcat_h, Wcat_l, bihh,
        c, h, hcur_h, hcur_l);
    // energy partials: h @ attn_W^T, split-K4 (256 each)
    gemm3<0><<<256, 256, 0, stream>>>(
        hcur_h, hcur_l, 2048, attnW_h, attnW_l, 1024,
        256, Pe, 1024, 4, 4, nullptr, nullptr, nullptr);
    // fused energy-reduce + flash attention + merge -> hcur[1024:2048], wts
    attn_fused<<<BB, 512, 0, stream>>>(Pe, attn_b, enc, hcur_h, hcur_l, wts);
    // co = tanh([h|ctx] @ concat_W^T + concat_b), fused split epilogue
    gemm3<1><<<64, 256, 0, stream>>>(
        hcur_h, hcur_l, 2048, catW_h, catW_l, 2048,
        2048, nullptr, 1024, 4, 1, concat_b, co_h, co_l);
    // logits partials: co @ lin_W^T, split-K2 (512 each)
    gemm3<0><<<256, 256, 0, stream>>>(
        co_h, co_l, 1024, linW_h, linW_l, 1024,
        512, Pl, 2048, 4, 2, nullptr, nullptr, nullptr);
    // logits reduce + bias + dec write + greedy argmax
    argmax_reduce<<<BB, 256, 0, stream>>>(Pl, lin_b, dec, step * VV, inp);
  }
}

// Round 9
// 904.588 us; speedup vs baseline: 1.2141x; 1.0569x over previous
//
#include <hip/hip_runtime.h>
#include <math.h>

#define HH 1024
#define VV 2048
#define BB 256
#define SS 512
#define NSTEPS 6
#define SOS 129

typedef __attribute__((ext_vector_type(8))) __bf16 bf16x8;
typedef __attribute__((ext_vector_type(4))) __bf16 bf16x4;
typedef __attribute__((ext_vector_type(2))) __bf16 bf16x2;
typedef __attribute__((ext_vector_type(4))) float f32x4;

__device__ __forceinline__ float sigmoidf_(float x) { return 1.0f / (1.0f + expf(-x)); }

__device__ __forceinline__ void split1(float x, __bf16& h, __bf16& l) {
  h = (__bf16)x;
  l = (__bf16)(x - (float)h);
}

// async global->LDS, 16B per lane; LDS dest must be wave-uniform base.
__device__ __forceinline__ void gll16(const __bf16* src, __bf16* ldst) {
  __builtin_amdgcn_global_load_lds(
      (const __attribute__((address_space(1))) unsigned*)(const void*)src,
      (__attribute__((address_space(3))) unsigned*)(void*)ldst, 16, 0, 0);
}

// ---------------------------------------------------------------------------
// Split-bf16 MFMA GEMM, double-buffered, global_load_lds staging, SPLIT-K,
// XCD-aware 1-D grid decode. P[z][m][n] = sum_{k in chunk z} A[m][k]*B[n][k]
// (raw fp32 partials; bias/activation in the consuming reduce kernel).
// Tile 64x64, BK=64, 256 threads (4 waves), wave-tile 32x32.
// AMODE 0: A = Ah/Al, row stride lda.
// AMODE 1: A = [emb[aidx[r]] | hcat[r][0:1024]] (gates GEMM, K=2048).
// ---------------------------------------------------------------------------
template<int AMODE>
__global__ __launch_bounds__(256) void gemm3(
    const __bf16* __restrict__ Ah, const __bf16* __restrict__ Al, int lda,
    const __bf16* __restrict__ A1h, const __bf16* __restrict__ A1l,
    const int* __restrict__ aidx,
    const __bf16* __restrict__ Bh, const __bf16* __restrict__ Bl, int K,
    int kLen, float* __restrict__ P, int ldc,
    int ny, int nz)
{
  __shared__ __align__(16) __bf16 lds[2][4][64 * 64];  // 64 KB
  const int t = threadIdx.x, lane = t & 63, wv = t >> 6;

  // XCD-chunked decode, x-major work order (all y,z of an x share an XCD)
  const int chunk = (int)(gridDim.x >> 3);
  const int w = (blockIdx.x & 7) * chunk + (blockIdx.x >> 3);
  const int bz = w % nz;
  const int by = (w / nz) % ny;
  const int bx = w / (nz * ny);

  const int row0 = by * 64, col0 = bx * 64;

  const int sslot = lane & 7;
  const int srw   = lane >> 3;
  int sw[2];
  const __bf16 *arh[2], *arl[2], *a1h[2], *a1l[2], *brh[2], *brl[2];
#pragma unroll
  for (int hf = 0; hf < 2; ++hf) {
    const int tr = wv * 16 + hf * 8 + srw;
    sw[hf] = (sslot ^ (tr & 7)) << 3;
    const int ar = row0 + tr;
    if (AMODE == 1) {
      const int r = aidx[ar];
      arh[hf] = Ah + (size_t)r * HH;
      arl[hf] = Al + (size_t)r * HH;
      a1h[hf] = A1h + (size_t)ar * 2048;
      a1l[hf] = A1l + (size_t)ar * 2048;
    } else {
      arh[hf] = Ah + (size_t)ar * lda;
      arl[hf] = Al + (size_t)ar * lda;
    }
    const int br = col0 + tr;
    brh[hf] = Bh + (size_t)br * K;
    brl[hf] = Bl + (size_t)br * K;
  }

  const int wr = (wv >> 1) * 32, wc = (wv & 1) * 32;
  const int fr = lane & 15, kb = (lane >> 4) * 8;

  const f32x4 fz = {0.f, 0.f, 0.f, 0.f};
  f32x4 acc[2][2] = {{fz, fz}, {fz, fz}};

  const int tBeg = (bz * kLen) >> 6;
  const int nt = kLen >> 6;

  auto stage = [&](int tIdx, int bi) {
    const int k0 = tIdx << 6;
#pragma unroll
    for (int hf = 0; hf < 2; ++hf) {
      const int rb = (wv * 16 + hf * 8) * 64;
      const __bf16 *sa_h, *sa_l;
      if (AMODE == 1 && k0 >= HH) {
        sa_h = a1h[hf] + (k0 - HH) + sw[hf];
        sa_l = a1l[hf] + (k0 - HH) + sw[hf];
      } else {
        sa_h = arh[hf] + k0 + sw[hf];
        sa_l = arl[hf] + k0 + sw[hf];
      }
      gll16(sa_h, &lds[bi][0][rb]);
      gll16(sa_l, &lds[bi][1][rb]);
      gll16(brh[hf] + k0 + sw[hf], &lds[bi][2][rb]);
      gll16(brl[hf] + k0 + sw[hf], &lds[bi][3][rb]);
    }
  };

  auto compute = [&](int bi) {
#pragma unroll
    for (int kc = 0; kc < 2; ++kc) {
      const int e = kc * 32 + kb;
      bf16x8 a_h[2], a_l[2], b_h[2], b_l[2];
#pragma unroll
      for (int i = 0; i < 2; ++i) {
        const int ra = wr + i * 16 + fr;
        const int ia = ra * 64 + (e ^ ((ra & 7) << 3));
        a_h[i] = *(const bf16x8*)&lds[bi][0][ia];
        a_l[i] = *(const bf16x8*)&lds[bi][1][ia];
        const int rb2 = wc + i * 16 + fr;
        const int ib = rb2 * 64 + (e ^ ((rb2 & 7) << 3));
        b_h[i] = *(const bf16x8*)&lds[bi][2][ib];
        b_l[i] = *(const bf16x8*)&lds[bi][3][ib];
      }
#pragma unroll
      for (int i = 0; i < 2; ++i)
#pragma unroll
        for (int j = 0; j < 2; ++j)
          acc[i][j] = __builtin_amdgcn_mfma_f32_16x16x32_bf16(a_h[i], b_h[j], acc[i][j], 0, 0, 0);
#pragma unroll
      for (int i = 0; i < 2; ++i)
#pragma unroll
        for (int j = 0; j < 2; ++j)
          acc[i][j] = __builtin_amdgcn_mfma_f32_16x16x32_bf16(a_h[i], b_l[j], acc[i][j], 0, 0, 0);
#pragma unroll
      for (int i = 0; i < 2; ++i)
#pragma unroll
        for (int j = 0; j < 2; ++j)
          acc[i][j] = __builtin_amdgcn_mfma_f32_16x16x32_bf16(a_l[i], b_h[j], acc[i][j], 0, 0, 0);
    }
  };

  stage(tBeg, 0);
  __syncthreads();
  int cur = 0;
  for (int tk = 0; tk < nt; ++tk) {
    if (tk + 1 < nt) stage(tBeg + tk + 1, cur ^ 1);
    compute(cur);
    __syncthreads();
    cur ^= 1;
  }

  float* Cp = P + (size_t)bz * 256 * ldc;
#pragma unroll
  for (int i = 0; i < 2; ++i)
#pragma unroll
    for (int j = 0; j < 2; ++j) {
      const int col = col0 + wc + j * 16 + fr;
#pragma unroll
      for (int r = 0; r < 4; ++r) {
        const int row = row0 + wr + i * 16 + (lane >> 4) * 4 + r;
        Cp[(size_t)row * ldc + col] = acc[i][j][r];
      }
    }
}

// ---------------------------------------------------------------------------
// One-shot conversion of all fp32 weights (+ embedding) to split hi/lo bf16.
// ---------------------------------------------------------------------------
__global__ __launch_bounds__(256) void conv_all(
    const float* __restrict__ W_ih, const float* __restrict__ W_hh,
    const float* __restrict__ attn_W, const float* __restrict__ concat_W,
    const float* __restrict__ lin_W, const float* __restrict__ emb,
    __bf16* __restrict__ Wcat_h, __bf16* __restrict__ Wcat_l,
    __bf16* __restrict__ attnW_h, __bf16* __restrict__ attnW_l,
    __bf16* __restrict__ catW_h, __bf16* __restrict__ catW_l,
    __bf16* __restrict__ linW_h, __bf16* __restrict__ linW_l,
    __bf16* __restrict__ emb_h, __bf16* __restrict__ emb_l)
{
  const int i = blockIdx.x * 256 + threadIdx.x;
  const float* s;
  __bf16 *dh, *dl;
  size_t so, dofs;
  if (i < 2097152) {
    const int ii = i & 1048575;
    const int r = ii >> 8, cp = (ii & 255) << 2;
    s = (i < 1048576) ? W_ih : W_hh;
    so = (size_t)r * 1024 + cp;
    dh = Wcat_h; dl = Wcat_l;
    dofs = (size_t)r * 2048 + ((i < 1048576) ? 0 : 1024) + cp;
  } else if (i < 2359296) {
    const size_t ii = (size_t)(i - 2097152) << 2;
    s = attn_W; so = ii; dh = attnW_h; dl = attnW_l; dofs = ii;
  } else if (i < 2883584) {
    const size_t ii = (size_t)(i - 2359296) << 2;
    s = concat_W; so = ii; dh = catW_h; dl = catW_l; dofs = ii;
  } else if (i < 3407872) {
    const size_t ii = (size_t)(i - 2883584) << 2;
    s = lin_W; so = ii; dh = linW_h; dl = linW_l; dofs = ii;
  } else {
    const size_t ii = (size_t)(i - 3407872) << 2;
    s = emb; so = ii; dh = emb_h; dl = emb_l; dofs = ii;
  }
  const float4 v = *(const float4*)(s + so);
  __bf16 h0, l0, h1, l1, h2, l2, h3, l3;
  split1(v.x, h0, l0); split1(v.y, h1, l1); split1(v.z, h2, l2); split1(v.w, h3, l3);
  *(bf16x4*)&dh[dofs] = bf16x4{h0, h1, h2, h3};
  *(bf16x4*)&dl[dofs] = bf16x4{l0, l1, l2, l3};
}

// ---------------------------------------------------------------------------
// gates reduce (4 split-K chunks) + bias + LSTM elementwise; emits h split.
// ---------------------------------------------------------------------------
__global__ __launch_bounds__(256) void lstm_reduce(
    const float* __restrict__ Pg, const float* __restrict__ bihh,
    float* c, float* h,
    __bf16* __restrict__ hcat_h, __bf16* __restrict__ hcat_l)
{
  const int id = blockIdx.x * 256 + threadIdx.x;  // 0..262143
  const int b = id >> 10, j = id & 1023;
  const size_t base = (size_t)b * 4096 + j;
  const size_t cs = (size_t)256 * 4096;
  float ig = bihh[j], fg = bihh[j + 1024], gg = bihh[j + 2048], og = bihh[j + 3072];
#pragma unroll
  for (int z = 0; z < 4; ++z) {
    ig += Pg[base + z * cs];
    fg += Pg[base + z * cs + 1024];
    gg += Pg[base + z * cs + 2048];
    og += Pg[base + z * cs + 3072];
  }
  const float cn = sigmoidf_(fg) * c[id] + sigmoidf_(ig) * tanhf(gg);
  const float hn = sigmoidf_(og) * tanhf(cn);
  c[id] = cn;
  h[id] = hn;
  __bf16 hh, hl;
  split1(hn, hh, hl);
  hcat_h[(size_t)b * 2048 + j] = hh;
  hcat_l[(size_t)b * 2048 + j] = hl;
}

// ---------------------------------------------------------------------------
// Single-pass attention. WG (b, half) covers 256 enc rows; each of the 8
// waves is an INDEPENDENT online-softmax unit over its own 32 rows:
// score from register-resident row, then ctx += e*row into a private LDS
// slice (no barriers in the loop). Energy = sum of 4 split-K partials + bias
// (fused reduce). Defer-max (THR=8). 8-way exact merge at the end.
// DEPTH-2 row prefetch: two enc rows in flight per wave (R9).
// All enc loads non-temporal (R7: enc is a pure stream).
// ---------------------------------------------------------------------------
__global__ __launch_bounds__(512) void attn_part(
    const float* __restrict__ Pe, const float* __restrict__ attn_b,
    const float* __restrict__ enc,
    float* __restrict__ pml, float* __restrict__ pcacc, float* __restrict__ scb)
{
  const int b = blockIdx.x >> 1, half = blockIdx.x & 1;
  const int base = half * 256;
  const int t = threadIdx.x, lane = t & 63, wv = t >> 6;
  __shared__ __align__(16) float ctxa[8][1024];  // 32 KB, one slice per wave
  __shared__ float wml[8][2];
  const float* encb = enc + (size_t)b * (SS * HH);

  // energy reduce: er = sum of 4 chunks + attn_b
  f32x4 er[4];
  {
    const f32x4* P4 = (const f32x4*)Pe;
    const f32x4* B4 = (const f32x4*)attn_b;
#pragma unroll
    for (int i = 0; i < 4; ++i) {
      const size_t idx = (size_t)b * 256 + lane + 64 * i;
      f32x4 v = P4[idx];
      const f32x4 v1 = P4[idx + 65536], v2 = P4[idx + 131072], v3 = P4[idx + 196608];
      const f32x4 bb = B4[lane + 64 * i];
      v.x += v1.x + v2.x + v3.x + bb.x; v.y += v1.y + v2.y + v3.y + bb.y;
      v.z += v1.z + v2.z + v3.z + bb.z; v.w += v1.w + v2.w + v3.w + bb.w;
      er[i] = v;
    }
  }

  // zero this wave's ctx slice
  f32x4* cx = (f32x4*)ctxa[wv];
#pragma unroll
  for (int i = 0; i < 4; ++i) cx[lane + 64 * i] = f32x4{0.f, 0.f, 0.f, 0.f};

  float m = -INFINITY, lw = 0.0f;
  const int r0 = base + wv * 32;  // this wave's 32 rows

  // depth-2 register prefetch pipeline
  f32x4 r4[4], r4n[4];
  {
    const f32x4* row0p = (const f32x4*)(encb + (size_t)r0 * HH);
    const f32x4* row1p = (const f32x4*)(encb + (size_t)(r0 + 1) * HH);
#pragma unroll
    for (int i = 0; i < 4; ++i) r4[i]  = __builtin_nontemporal_load(&row0p[lane + 64 * i]);
#pragma unroll
    for (int i = 0; i < 4; ++i) r4n[i] = __builtin_nontemporal_load(&row1p[lane + 64 * i]);
  }

  for (int s = 0; s < 32; ++s) {
    f32x4 r4nn[4];
    if (s + 2 < 32) {
      const f32x4* row = (const f32x4*)(encb + (size_t)(r0 + s + 2) * HH);
#pragma unroll
      for (int i = 0; i < 4; ++i) r4nn[i] = __builtin_nontemporal_load(&row[lane + 64 * i]);
    }
    float p = 0.0f;
#pragma unroll
    for (int i = 0; i < 4; ++i)
      p += r4[i].x * er[i].x + r4[i].y * er[i].y + r4[i].z * er[i].z + r4[i].w * er[i].w;
#pragma unroll
    for (int off = 32; off; off >>= 1) p += __shfl_xor(p, off);
    if (lane == 0) scb[(size_t)b * SS + r0 + s] = p;

    if (p > m + 8.0f) {  // defer-max rescale (wave-uniform; exact algebra)
      const float alpha = expf(m - p);  // first iter: exp(-inf)=0, ctx already 0
      lw *= alpha;
#pragma unroll
      for (int i = 0; i < 4; ++i) {
        f32x4 v = cx[lane + 64 * i];
        v.x *= alpha; v.y *= alpha; v.z *= alpha; v.w *= alpha;
        cx[lane + 64 * i] = v;
      }
      m = p;
    }
    const float e = expf(p - m);
    lw += e;
#pragma unroll
    for (int i = 0; i < 4; ++i) {
      f32x4 v = cx[lane + 64 * i];
      v.x += e * r4[i].x; v.y += e * r4[i].y; v.z += e * r4[i].z; v.w += e * r4[i].w;
      cx[lane + 64 * i] = v;
    }
#pragma unroll
    for (int i = 0; i < 4; ++i) { r4[i] = r4n[i]; r4n[i] = r4nn[i]; }
  }

  if (lane == 0) { wml[wv][0] = m; wml[wv][1] = lw; }
  __syncthreads();

  // 8-way merge (all threads)
  float M = -INFINITY;
#pragma unroll
  for (int w = 0; w < 8; ++w) M = fmaxf(M, wml[w][0]);
  float ew[8];
  float L = 0.0f;
#pragma unroll
  for (int w = 0; w < 8; ++w) { ew[w] = expf(wml[w][0] - M); L += wml[w][1] * ew[w]; }

  float2 acc = {0.0f, 0.0f};
#pragma unroll
  for (int w = 0; w < 8; ++w) {
    const float2 v = ((const float2*)ctxa[w])[t];
    acc.x += ew[w] * v.x; acc.y += ew[w] * v.y;
  }
  ((float2*)(pcacc + ((size_t)b * 2 + half) * HH))[t] = acc;
  if (t == 0) { pml[(b * 2 + half) * 2 + 0] = M; pml[(b * 2 + half) * 2 + 1] = L; }
}

// Merge the two halves: context -> hcat[:,1024:], weights -> wout.
__global__ __launch_bounds__(512) void attn_merge(
    const float* __restrict__ pml, const float* __restrict__ pcacc,
    const float* __restrict__ scb,
    __bf16* __restrict__ hcat_h, __bf16* __restrict__ hcat_l,
    float* __restrict__ wout)
{
  const int b = blockIdx.x, t = threadIdx.x;
  const float m0 = pml[b * 4 + 0], l0 = pml[b * 4 + 1];
  const float m1 = pml[b * 4 + 2], l1 = pml[b * 4 + 3];
  const float M = fmaxf(m0, m1);
  const float w0 = expf(m0 - M), w1 = expf(m1 - M);
  const float inv = 1.0f / (l0 * w0 + l1 * w1);
  const float2 c0 = ((const float2*)(pcacc + (size_t)b * 2048))[t];
  const float2 c1 = ((const float2*)(pcacc + (size_t)b * 2048 + 1024))[t];
  const float ox = (c0.x * w0 + c1.x * w1) * inv;
  const float oy = (c0.y * w0 + c1.y * w1) * inv;
  __bf16 h0, lo0, h1, lo1;
  split1(ox, h0, lo0); split1(oy, h1, lo1);
  const size_t ob = (size_t)b * 2048 + 1024 + 2 * t;
  *(bf16x2*)&hcat_h[ob] = bf16x2{h0, h1};
  *(bf16x2*)&hcat_l[ob] = bf16x2{lo0, lo1};
  wout[(size_t)b * SS + t] = expf(scb[(size_t)b * SS + t] - M) * inv;
}

// ---------------------------------------------------------------------------
// co reduce (4 chunks) + bias + tanh + split -> co_h/co_l.
// ---------------------------------------------------------------------------
__global__ __launch_bounds__(256) void co_reduce(
    const float* __restrict__ Pc, const float* __restrict__ concat_b,
    __bf16* __restrict__ co_h, __bf16* __restrict__ co_l)
{
  const int id = blockIdx.x * 256 + threadIdx.x;  // float4 group, 0..65535
  const size_t e4 = (size_t)id << 2;
  const int j = (int)(e4 & 1023);
  const size_t cs = (size_t)256 * 1024;
  float4 v = *(const float4*)(Pc + e4);
  const float4 v1 = *(const float4*)(Pc + e4 + cs);
  const float4 v2 = *(const float4*)(Pc + e4 + 2 * cs);
  const float4 v3 = *(const float4*)(Pc + e4 + 3 * cs);
  const float4 bb = *(const float4*)(concat_b + j);
  v.x = tanhf(v.x + v1.x + v2.x + v3.x + bb.x);
  v.y = tanhf(v.y + v1.y + v2.y + v3.y + bb.y);
  v.z = tanhf(v.z + v1.z + v2.z + v3.z + bb.z);
  v.w = tanhf(v.w + v1.w + v2.w + v3.w + bb.w);
  __bf16 h0, l0, h1, l1, h2, l2, h3, l3;
  split1(v.x, h0, l0); split1(v.y, h1, l1); split1(v.z, h2, l2); split1(v.w, h3, l3);
  *(bf16x4*)&co_h[e4] = bf16x4{h0, h1, h2, h3};
  *(bf16x4*)&co_l[e4] = bf16x4{l0, l1, l2, l3};
}

// ---------------------------------------------------------------------------
// logits reduce (4 chunks) + bias -> dec output, fused greedy argmax
// (first-index tie-break, deterministic).
// ---------------------------------------------------------------------------
__global__ __launch_bounds__(256) void argmax_reduce(
    const float* __restrict__ Pl, const float* __restrict__ lin_b,
    float* __restrict__ dec, int coff, int* __restrict__ inp)
{
  const int b = blockIdx.x, t = threadIdx.x;
  const size_t rb = (size_t)b * 2048;
  const size_t cs = (size_t)256 * 2048;
  float* drow = dec + (size_t)b * (NSTEPS * VV) + coff;
  float best = -INFINITY; int bi = 0;
  for (int j = t; j < VV; j += 256) {
    float v = lin_b[j];
#pragma unroll
    for (int z = 0; z < 4; ++z) v += Pl[rb + z * cs + j];
    drow[j] = v;
    if (v > best) { best = v; bi = j; }
  }
  __shared__ float vs[256];
  __shared__ int   is[256];
  vs[t] = best; is[t] = bi;
  __syncthreads();
  for (int stp = 128; stp; stp >>= 1) {
    if (t < stp) {
      const float v2 = vs[t + stp]; const int i2 = is[t + stp];
      if (v2 > vs[t] || (v2 == vs[t] && i2 < is[t])) { vs[t] = v2; is[t] = i2; }
    }
    __syncthreads();
  }
  if (t == 0) inp[b] = is[0];
}

// ---------------------------------------------------------------------------
// Init: h,c <- h0,c0 ; h split into hcat[:,0:1024]; combined bias; SOS inp.
// ---------------------------------------------------------------------------
__global__ __launch_bounds__(256) void init_kernel(
    const float* __restrict__ h0, const float* __restrict__ c0,
    float* h, float* c,
    const float* __restrict__ b_ih, const float* __restrict__ b_hh,
    float* bihh, int* inp,
    __bf16* __restrict__ hcat_h, __bf16* __restrict__ hcat_l)
{
  const int id = blockIdx.x * 256 + threadIdx.x;
  if (id < BB * HH) {
    const float hv = h0[id];
    h[id] = hv;
    c[id] = c0[id];
    __bf16 hh, hl;
    split1(hv, hh, hl);
    const int b = id >> 10, j = id & 1023;
    hcat_h[(size_t)b * 2048 + j] = hh;
    hcat_l[(size_t)b * 2048 + j] = hl;
  }
  if (id < 4096) bihh[id] = b_ih[id] + b_hh[id];
  if (id < BB) inp[id] = SOS;
}

extern "C" void kernel_launch(void* const* d_in, const int* in_sizes, int n_in,
                              void* d_out, int out_size, void* d_ws, size_t ws_size,
                              hipStream_t stream)
{
  (void)in_sizes; (void)n_in; (void)out_size; (void)ws_size;
  const float* enc      = (const float*)d_in[0];
  const float* h0       = (const float*)d_in[1];
  const float* c0       = (const float*)d_in[2];
  const float* emb      = (const float*)d_in[3];
  const float* W_ih     = (const float*)d_in[4];
  const float* W_hh     = (const float*)d_in[5];
  const float* b_ih     = (const float*)d_in[6];
  const float* b_hh     = (const float*)d_in[7];
  const float* attn_W   = (const float*)d_in[8];
  const float* attn_b   = (const float*)d_in[9];
  const float* concat_W = (const float*)d_in[10];
  const float* concat_b = (const float*)d_in[11];
  const float* lin_W    = (const float*)d_in[12];
  const float* lin_b    = (const float*)d_in[13];

  float* out = (float*)d_out;
  float* dec = out;                                  // [256][6][2048]
  float* h   = out + (size_t)BB * NSTEPS * VV;       // [256][1024]
  float* c   = h + (size_t)BB * HH;                  // [256][1024]
  float* wts = c + (size_t)BB * HH;                  // [256][512]

  char* w = (char*)d_ws;
  auto alloc = [&](size_t bytes) { char* p = w; w += (bytes + 255) & ~255ull; return p; };
  float*  bihh    = (float*)alloc(4096 * 4);
  int*    inp     = (int*)alloc(BB * 4);
  __bf16* Wcat_h  = (__bf16*)alloc((size_t)4096 * 2048 * 2);
  __bf16* Wcat_l  = (__bf16*)alloc((size_t)4096 * 2048 * 2);
  __bf16* attnW_h = (__bf16*)alloc((size_t)1024 * 1024 * 2);
  __bf16* attnW_l = (__bf16*)alloc((size_t)1024 * 1024 * 2);
  __bf16* catW_h  = (__bf16*)alloc((size_t)1024 * 2048 * 2);
  __bf16* catW_l  = (__bf16*)alloc((size_t)1024 * 2048 * 2);
  __bf16* linW_h  = (__bf16*)alloc((size_t)2048 * 1024 * 2);
  __bf16* linW_l  = (__bf16*)alloc((size_t)2048 * 1024 * 2);
  __bf16* emb_h   = (__bf16*)alloc((size_t)VV * HH * 2);
  __bf16* emb_l   = (__bf16*)alloc((size_t)VV * HH * 2);
  __bf16* hcat_h  = (__bf16*)alloc((size_t)BB * 2048 * 2);
  __bf16* hcat_l  = (__bf16*)alloc((size_t)BB * 2048 * 2);
  __bf16* co_h    = (__bf16*)alloc((size_t)BB * 1024 * 2);
  __bf16* co_l    = (__bf16*)alloc((size_t)BB * 1024 * 2);
  float*  pml     = (float*)alloc(BB * 4 * 4);
  float*  pcacc   = (float*)alloc((size_t)BB * 2 * HH * 4);
  float*  scb     = (float*)alloc((size_t)BB * SS * 4);
  float*  Pg      = (float*)alloc((size_t)4 * BB * 4096 * 4);  // gates partials (K4)
  float*  Pe      = (float*)alloc((size_t)4 * BB * 1024 * 4);  // energy partials
  float*  Pc      = (float*)alloc((size_t)4 * BB * 1024 * 4);  // concat partials
  float*  Pl      = (float*)alloc((size_t)4 * BB * 2048 * 4);  // logits partials (K4)

  conv_all<<<15360, 256, 0, stream>>>(W_ih, W_hh, attn_W, concat_W, lin_W, emb,
                                      Wcat_h, Wcat_l, attnW_h, attnW_l,
                                      catW_h, catW_l, linW_h, linW_l, emb_h, emb_l);
  init_kernel<<<1024, 256, 0, stream>>>(h0, c0, h, c, b_ih, b_hh, bihh, inp,
                                        hcat_h, hcat_l);

  for (int step = 0; step < NSTEPS; ++step) {
    // gates partials: [emb[inp]|h] @ Wcat^T, split-K4 (512 each), XCD-chunked
    gemm3<1><<<1024, 256, 0, stream>>>(
        emb_h, emb_l, HH, hcat_h, hcat_l, inp, Wcat_h, Wcat_l, 2048,
        512, Pg, 4096, 4, 4);
    lstm_reduce<<<1024, 256, 0, stream>>>(Pg, bihh, c, h, hcat_h, hcat_l);
    // energy partials: h @ attn_W^T, split-K4 (256 each)
    gemm3<0><<<256, 256, 0, stream>>>(
        hcat_h, hcat_l, 2048, nullptr, nullptr, nullptr, attnW_h, attnW_l, 1024,
        256, Pe, 1024, 4, 4);
    // fused energy-reduce + single-pass flash attention (depth-2 prefetch)
    attn_part<<<2 * BB, 512, 0, stream>>>(Pe, attn_b, enc, pml, pcacc, scb);
    attn_merge<<<BB, 512, 0, stream>>>(pml, pcacc, scb, hcat_h, hcat_l, wts);
    // concat partials: [h|ctx] @ concat_W^T, split-K4 (512 each)
    gemm3<0><<<256, 256, 0, stream>>>(
        hcat_h, hcat_l, 2048, nullptr, nullptr, nullptr, catW_h, catW_l, 2048,
        512, Pc, 1024, 4, 4);
    co_reduce<<<256, 256, 0, stream>>>(Pc, concat_b, co_h, co_l);
    // logits partials: co @ lin_W^T, split-K4 (256 each)
    gemm3<0><<<512, 256, 0, stream>>>(
        co_h, co_l, 1024, nullptr, nullptr, nullptr, linW_h, linW_l, 1024,
        256, Pl, 2048, 4, 4);
    argmax_reduce<<<BB, 256, 0, stream>>>(Pl, lin_b, dec, step * VV, inp);
  }
}

// Round 10
// 878.796 us; speedup vs baseline: 1.2497x; 1.0293x over previous
//
#include <hip/hip_runtime.h>
#include <math.h>

#define HH 1024
#define VV 2048
#define BB 256
#define SS 512
#define NSTEPS 6
#define SOS 129

typedef __attribute__((ext_vector_type(8))) __bf16 bf16x8;
typedef __attribute__((ext_vector_type(4))) __bf16 bf16x4;
typedef __attribute__((ext_vector_type(2))) __bf16 bf16x2;
typedef __attribute__((ext_vector_type(4))) float f32x4;

__device__ __forceinline__ float sigmoidf_(float x) { return 1.0f / (1.0f + expf(-x)); }

__device__ __forceinline__ void split1(float x, __bf16& h, __bf16& l) {
  h = (__bf16)x;
  l = (__bf16)(x - (float)h);
}

// async global->LDS, 16B per lane; LDS dest must be wave-uniform base.
__device__ __forceinline__ void gll16(const __bf16* src, __bf16* ldst) {
  __builtin_amdgcn_global_load_lds(
      (const __attribute__((address_space(1))) unsigned*)(const void*)src,
      (__attribute__((address_space(3))) unsigned*)(void*)ldst, 16, 0, 0);
}

// ---------------------------------------------------------------------------
// Split-bf16 MFMA GEMM, double-buffered, global_load_lds staging, SPLIT-K.
// P[z][m][n] = sum_{k in chunk z} A[m][k]*B[n][k]   (raw fp32 partials,
// bias/activation applied by the consuming reduce kernel).
// Tile 64x64, BK=64, 256 threads (4 waves), wave-tile 32x32, chunk = kLen.
// AMODE 0: A = Ah/Al, row stride lda.
// AMODE 1: A = [emb[aidx[r]] | hcat[r][0:1024]] (gates GEMM, K=2048).
// ---------------------------------------------------------------------------
template<int AMODE>
__global__ __launch_bounds__(256) void gemm3(
    const __bf16* __restrict__ Ah, const __bf16* __restrict__ Al, int lda,
    const __bf16* __restrict__ A1h, const __bf16* __restrict__ A1l,
    const int* __restrict__ aidx,
    const __bf16* __restrict__ Bh, const __bf16* __restrict__ Bl, int K,
    int kLen, float* __restrict__ P, int ldc)
{
  __shared__ __align__(16) __bf16 lds[2][4][64 * 64];  // 64 KB
  const int t = threadIdx.x, lane = t & 63, wv = t >> 6;
  const int row0 = blockIdx.y * 64, col0 = blockIdx.x * 64;

  const int sslot = lane & 7;
  const int srw   = lane >> 3;
  int sw[2];
  const __bf16 *arh[2], *arl[2], *a1h[2], *a1l[2], *brh[2], *brl[2];
#pragma unroll
  for (int hf = 0; hf < 2; ++hf) {
    const int tr = wv * 16 + hf * 8 + srw;
    sw[hf] = (sslot ^ (tr & 7)) << 3;
    const int ar = row0 + tr;
    if (AMODE == 1) {
      const int r = aidx[ar];
      arh[hf] = Ah + (size_t)r * HH;
      arl[hf] = Al + (size_t)r * HH;
      a1h[hf] = A1h + (size_t)ar * 2048;
      a1l[hf] = A1l + (size_t)ar * 2048;
    } else {
      arh[hf] = Ah + (size_t)ar * lda;
      arl[hf] = Al + (size_t)ar * lda;
    }
    const int br = col0 + tr;
    brh[hf] = Bh + (size_t)br * K;
    brl[hf] = Bl + (size_t)br * K;
  }

  const int wr = (wv >> 1) * 32, wc = (wv & 1) * 32;
  const int fr = lane & 15, kb = (lane >> 4) * 8;

  const f32x4 fz = {0.f, 0.f, 0.f, 0.f};
  f32x4 acc[2][2] = {{fz, fz}, {fz, fz}};

  const int tBeg = (blockIdx.z * kLen) >> 6;
  const int nt = kLen >> 6;

  auto stage = [&](int tIdx, int bi) {
    const int k0 = tIdx << 6;
#pragma unroll
    for (int hf = 0; hf < 2; ++hf) {
      const int rb = (wv * 16 + hf * 8) * 64;
      const __bf16 *sa_h, *sa_l;
      if (AMODE == 1 && k0 >= HH) {
        sa_h = a1h[hf] + (k0 - HH) + sw[hf];
        sa_l = a1l[hf] + (k0 - HH) + sw[hf];
      } else {
        sa_h = arh[hf] + k0 + sw[hf];
        sa_l = arl[hf] + k0 + sw[hf];
      }
      gll16(sa_h, &lds[bi][0][rb]);
      gll16(sa_l, &lds[bi][1][rb]);
      gll16(brh[hf] + k0 + sw[hf], &lds[bi][2][rb]);
      gll16(brl[hf] + k0 + sw[hf], &lds[bi][3][rb]);
    }
  };

  auto compute = [&](int bi) {
#pragma unroll
    for (int kc = 0; kc < 2; ++kc) {
      const int e = kc * 32 + kb;
      bf16x8 a_h[2], a_l[2], b_h[2], b_l[2];
#pragma unroll
      for (int i = 0; i < 2; ++i) {
        const int ra = wr + i * 16 + fr;
        const int ia = ra * 64 + (e ^ ((ra & 7) << 3));
        a_h[i] = *(const bf16x8*)&lds[bi][0][ia];
        a_l[i] = *(const bf16x8*)&lds[bi][1][ia];
        const int rb2 = wc + i * 16 + fr;
        const int ib = rb2 * 64 + (e ^ ((rb2 & 7) << 3));
        b_h[i] = *(const bf16x8*)&lds[bi][2][ib];
        b_l[i] = *(const bf16x8*)&lds[bi][3][ib];
      }
#pragma unroll
      for (int i = 0; i < 2; ++i)
#pragma unroll
        for (int j = 0; j < 2; ++j)
          acc[i][j] = __builtin_amdgcn_mfma_f32_16x16x32_bf16(a_h[i], b_h[j], acc[i][j], 0, 0, 0);
#pragma unroll
      for (int i = 0; i < 2; ++i)
#pragma unroll
        for (int j = 0; j < 2; ++j)
          acc[i][j] = __builtin_amdgcn_mfma_f32_16x16x32_bf16(a_h[i], b_l[j], acc[i][j], 0, 0, 0);
#pragma unroll
      for (int i = 0; i < 2; ++i)
#pragma unroll
        for (int j = 0; j < 2; ++j)
          acc[i][j] = __builtin_amdgcn_mfma_f32_16x16x32_bf16(a_l[i], b_h[j], acc[i][j], 0, 0, 0);
    }
  };

  stage(tBeg, 0);
  __syncthreads();
  int cur = 0;
  for (int tk = 0; tk < nt; ++tk) {
    if (tk + 1 < nt) stage(tBeg + tk + 1, cur ^ 1);
    compute(cur);
    __syncthreads();
    cur ^= 1;
  }

  float* Cp = P + (size_t)blockIdx.z * 256 * ldc;
#pragma unroll
  for (int i = 0; i < 2; ++i)
#pragma unroll
    for (int j = 0; j < 2; ++j) {
      const int col = col0 + wc + j * 16 + fr;
#pragma unroll
      for (int r = 0; r < 4; ++r) {
        const int row = row0 + wr + i * 16 + (lane >> 4) * 4 + r;
        Cp[(size_t)row * ldc + col] = acc[i][j][r];
      }
    }
}

// ---------------------------------------------------------------------------
// One-shot conversion of all fp32 weights (+ embedding) to split hi/lo bf16.
// ---------------------------------------------------------------------------
__global__ __launch_bounds__(256) void conv_all(
    const float* __restrict__ W_ih, const float* __restrict__ W_hh,
    const float* __restrict__ attn_W, const float* __restrict__ concat_W,
    const float* __restrict__ lin_W, const float* __restrict__ emb,
    __bf16* __restrict__ Wcat_h, __bf16* __restrict__ Wcat_l,
    __bf16* __restrict__ attnW_h, __bf16* __restrict__ attnW_l,
    __bf16* __restrict__ catW_h, __bf16* __restrict__ catW_l,
    __bf16* __restrict__ linW_h, __bf16* __restrict__ linW_l,
    __bf16* __restrict__ emb_h, __bf16* __restrict__ emb_l)
{
  const int i = blockIdx.x * 256 + threadIdx.x;
  const float* s;
  __bf16 *dh, *dl;
  size_t so, dofs;
  if (i < 2097152) {
    const int ii = i & 1048575;
    const int r = ii >> 8, cp = (ii & 255) << 2;
    s = (i < 1048576) ? W_ih : W_hh;
    so = (size_t)r * 1024 + cp;
    dh = Wcat_h; dl = Wcat_l;
    dofs = (size_t)r * 2048 + ((i < 1048576) ? 0 : 1024) + cp;
  } else if (i < 2359296) {
    const size_t ii = (size_t)(i - 2097152) << 2;
    s = attn_W; so = ii; dh = attnW_h; dl = attnW_l; dofs = ii;
  } else if (i < 2883584) {
    const size_t ii = (size_t)(i - 2359296) << 2;
    s = concat_W; so = ii; dh = catW_h; dl = catW_l; dofs = ii;
  } else if (i < 3407872) {
    const size_t ii = (size_t)(i - 2883584) << 2;
    s = lin_W; so = ii; dh = linW_h; dl = linW_l; dofs = ii;
  } else {
    const size_t ii = (size_t)(i - 3407872) << 2;
    s = emb; so = ii; dh = emb_h; dl = emb_l; dofs = ii;
  }
  const float4 v = *(const float4*)(s + so);
  __bf16 h0, l0, h1, l1, h2, l2, h3, l3;
  split1(v.x, h0, l0); split1(v.y, h1, l1); split1(v.z, h2, l2); split1(v.w, h3, l3);
  *(bf16x4*)&dh[dofs] = bf16x4{h0, h1, h2, h3};
  *(bf16x4*)&dl[dofs] = bf16x4{l0, l1, l2, l3};
}

// ---------------------------------------------------------------------------
// gates reduce (2 split-K chunks) + bias + LSTM elementwise; emits h split.
// ---------------------------------------------------------------------------
__global__ __launch_bounds__(256) void lstm_reduce(
    const float* __restrict__ Pg, const float* __restrict__ bihh,
    float* c, float* h,
    __bf16* __restrict__ hcat_h, __bf16* __restrict__ hcat_l)
{
  const int id = blockIdx.x * 256 + threadIdx.x;  // 0..262143
  const int b = id >> 10, j = id & 1023;
  const size_t base = (size_t)b * 4096 + j;
  const size_t cs = (size_t)256 * 4096;
  const float ig = Pg[base]        + Pg[base + cs]        + bihh[j];
  const float fg = Pg[base + 1024] + Pg[base + cs + 1024] + bihh[j + 1024];
  const float gg = Pg[base + 2048] + Pg[base + cs + 2048] + bihh[j + 2048];
  const float og = Pg[base + 3072] + Pg[base + cs + 3072] + bihh[j + 3072];
  const float cn = sigmoidf_(fg) * c[id] + sigmoidf_(ig) * tanhf(gg);
  const float hn = sigmoidf_(og) * tanhf(cn);
  c[id] = cn;
  h[id] = hn;
  __bf16 hh, hl;
  split1(hn, hh, hl);
  hcat_h[(size_t)b * 2048 + j] = hh;
  hcat_l[(size_t)b * 2048 + j] = hl;
}

// ---------------------------------------------------------------------------
// Single-pass attention. WG (b, half) covers 256 enc rows; each of the 8
// waves is an INDEPENDENT online-softmax unit over its own 32 rows:
// score from register-resident row, then ctx += e*row into a private LDS
// slice (no barriers in the loop). Energy = sum of 4 split-K partials + bias
// (fused reduce). Defer-max (THR=8) keeps rescales rare. 8-way exact merge
// at the end -> per-(b,half) (m,l,ctx).
// ---------------------------------------------------------------------------
__global__ __launch_bounds__(512) void attn_part(
    const float* __restrict__ Pe, const float* __restrict__ attn_b,
    const float* __restrict__ enc,
    float* __restrict__ pml, float* __restrict__ pcacc, float* __restrict__ scb)
{
  const int b = blockIdx.x >> 1, half = blockIdx.x & 1;
  const int base = half * 256;
  const int t = threadIdx.x, lane = t & 63, wv = t >> 6;
  __shared__ __align__(16) float ctxa[8][1024];  // 32 KB, one slice per wave
  __shared__ float wml[8][2];
  const float* encb = enc + (size_t)b * (SS * HH);

  // energy reduce: er = sum of 4 chunks + attn_b
  f32x4 er[4];
  {
    const f32x4* P4 = (const f32x4*)Pe;
    const f32x4* B4 = (const f32x4*)attn_b;
#pragma unroll
    for (int i = 0; i < 4; ++i) {
      const size_t idx = (size_t)b * 256 + lane + 64 * i;
      f32x4 v = P4[idx];
      const f32x4 v1 = P4[idx + 65536], v2 = P4[idx + 131072], v3 = P4[idx + 196608];
      const f32x4 bb = B4[lane + 64 * i];
      v.x += v1.x + v2.x + v3.x + bb.x; v.y += v1.y + v2.y + v3.y + bb.y;
      v.z += v1.z + v2.z + v3.z + bb.z; v.w += v1.w + v2.w + v3.w + bb.w;
      er[i] = v;
    }
  }

  // zero this wave's ctx slice
  f32x4* cx = (f32x4*)ctxa[wv];
#pragma unroll
  for (int i = 0; i < 4; ++i) cx[lane + 64 * i] = f32x4{0.f, 0.f, 0.f, 0.f};

  float m = -INFINITY, lw = 0.0f;
  const int r0 = base + wv * 32;  // this wave's 32 rows

  f32x4 r4[4];
  {
    const f32x4* row = (const f32x4*)(encb + (size_t)r0 * HH);
#pragma unroll
    for (int i = 0; i < 4; ++i) r4[i] = __builtin_nontemporal_load(&row[lane + 64 * i]);
  }

  for (int s = 0; s < 32; ++s) {
    f32x4 r4n[4];
    if (s + 1 < 32) {
      const f32x4* row = (const f32x4*)(encb + (size_t)(r0 + s + 1) * HH);
#pragma unroll
      for (int i = 0; i < 4; ++i) r4n[i] = __builtin_nontemporal_load(&row[lane + 64 * i]);
    }
    float p = 0.0f;
#pragma unroll
    for (int i = 0; i < 4; ++i)
      p += r4[i].x * er[i].x + r4[i].y * er[i].y + r4[i].z * er[i].z + r4[i].w * er[i].w;
#pragma unroll
    for (int off = 32; off; off >>= 1) p += __shfl_xor(p, off);
    if (lane == 0) scb[(size_t)b * SS + r0 + s] = p;

    if (p > m + 8.0f) {  // defer-max rescale (wave-uniform; exact algebra)
      const float alpha = expf(m - p);  // first iter: exp(-inf)=0, ctx already 0
      lw *= alpha;
#pragma unroll
      for (int i = 0; i < 4; ++i) {
        f32x4 v = cx[lane + 64 * i];
        v.x *= alpha; v.y *= alpha; v.z *= alpha; v.w *= alpha;
        cx[lane + 64 * i] = v;
      }
      m = p;
    }
    const float e = expf(p - m);
    lw += e;
#pragma unroll
    for (int i = 0; i < 4; ++i) {
      f32x4 v = cx[lane + 64 * i];
      v.x += e * r4[i].x; v.y += e * r4[i].y; v.z += e * r4[i].z; v.w += e * r4[i].w;
      cx[lane + 64 * i] = v;
    }
#pragma unroll
    for (int i = 0; i < 4; ++i) r4[i] = r4n[i];
  }

  if (lane == 0) { wml[wv][0] = m; wml[wv][1] = lw; }
  __syncthreads();

  // 8-way merge (all threads)
  float M = -INFINITY;
#pragma unroll
  for (int w = 0; w < 8; ++w) M = fmaxf(M, wml[w][0]);
  float ew[8];
  float L = 0.0f;
#pragma unroll
  for (int w = 0; w < 8; ++w) { ew[w] = expf(wml[w][0] - M); L += wml[w][1] * ew[w]; }

  float2 acc = {0.0f, 0.0f};
#pragma unroll
  for (int w = 0; w < 8; ++w) {
    const float2 v = ((const float2*)ctxa[w])[t];
    acc.x += ew[w] * v.x; acc.y += ew[w] * v.y;
  }
  ((float2*)(pcacc + ((size_t)b * 2 + half) * HH))[t] = acc;
  if (t == 0) { pml[(b * 2 + half) * 2 + 0] = M; pml[(b * 2 + half) * 2 + 1] = L; }
}

// Merge the two halves: context -> hcat[:,1024:], weights -> wout.
__global__ __launch_bounds__(512) void attn_merge(
    const float* __restrict__ pml, const float* __restrict__ pcacc,
    const float* __restrict__ scb,
    __bf16* __restrict__ hcat_h, __bf16* __restrict__ hcat_l,
    float* __restrict__ wout)
{
  const int b = blockIdx.x, t = threadIdx.x;
  const float m0 = pml[b * 4 + 0], l0 = pml[b * 4 + 1];
  const float m1 = pml[b * 4 + 2], l1 = pml[b * 4 + 3];
  const float M = fmaxf(m0, m1);
  const float w0 = expf(m0 - M), w1 = expf(m1 - M);
  const float inv = 1.0f / (l0 * w0 + l1 * w1);
  const float2 c0 = ((const float2*)(pcacc + (size_t)b * 2048))[t];
  const float2 c1 = ((const float2*)(pcacc + (size_t)b * 2048 + 1024))[t];
  const float ox = (c0.x * w0 + c1.x * w1) * inv;
  const float oy = (c0.y * w0 + c1.y * w1) * inv;
  __bf16 h0, lo0, h1, lo1;
  split1(ox, h0, lo0); split1(oy, h1, lo1);
  const size_t ob = (size_t)b * 2048 + 1024 + 2 * t;
  *(bf16x2*)&hcat_h[ob] = bf16x2{h0, h1};
  *(bf16x2*)&hcat_l[ob] = bf16x2{lo0, lo1};
  wout[(size_t)b * SS + t] = expf(scb[(size_t)b * SS + t] - M) * inv;
}

// ---------------------------------------------------------------------------
// co reduce (4 chunks) + bias + tanh + split -> co_h/co_l.
// ---------------------------------------------------------------------------
__global__ __launch_bounds__(256) void co_reduce(
    const float* __restrict__ Pc, const float* __restrict__ concat_b,
    __bf16* __restrict__ co_h, __bf16* __restrict__ co_l)
{
  const int id = blockIdx.x * 256 + threadIdx.x;  // float4 group, 0..65535
  const size_t e4 = (size_t)id << 2;
  const int j = (int)(e4 & 1023);
  const size_t cs = (size_t)256 * 1024;
  float4 v = *(const float4*)(Pc + e4);
  const float4 v1 = *(const float4*)(Pc + e4 + cs);
  const float4 v2 = *(const float4*)(Pc + e4 + 2 * cs);
  const float4 v3 = *(const float4*)(Pc + e4 + 3 * cs);
  const float4 bb = *(const float4*)(concat_b + j);
  v.x = tanhf(v.x + v1.x + v2.x + v3.x + bb.x);
  v.y = tanhf(v.y + v1.y + v2.y + v3.y + bb.y);
  v.z = tanhf(v.z + v1.z + v2.z + v3.z + bb.z);
  v.w = tanhf(v.w + v1.w + v2.w + v3.w + bb.w);
  __bf16 h0, l0, h1, l1, h2, l2, h3, l3;
  split1(v.x, h0, l0); split1(v.y, h1, l1); split1(v.z, h2, l2); split1(v.w, h3, l3);
  *(bf16x4*)&co_h[e4] = bf16x4{h0, h1, h2, h3};
  *(bf16x4*)&co_l[e4] = bf16x4{l0, l1, l2, l3};
}

// ---------------------------------------------------------------------------
// logits reduce (2 chunks) + bias -> dec output, fused greedy argmax
// (first-index tie-break, deterministic).
// ---------------------------------------------------------------------------
__global__ __launch_bounds__(256) void argmax_reduce(
    const float* __restrict__ Pl, const float* __restrict__ lin_b,
    float* __restrict__ dec, int coff, int* __restrict__ inp)
{
  const int b = blockIdx.x, t = threadIdx.x;
  const size_t rb = (size_t)b * 2048;
  const size_t cs = (size_t)256 * 2048;
  float* drow = dec + (size_t)b * (NSTEPS * VV) + coff;
  float best = -INFINITY; int bi = 0;
  for (int j = t; j < VV; j += 256) {
    const float v = Pl[rb + j] + Pl[rb + cs + j] + lin_b[j];
    drow[j] = v;
    if (v > best) { best = v; bi = j; }
  }
  __shared__ float vs[256];
  __shared__ int   is[256];
  vs[t] = best; is[t] = bi;
  __syncthreads();
  for (int stp = 128; stp; stp >>= 1) {
    if (t < stp) {
      const float v2 = vs[t + stp]; const int i2 = is[t + stp];
      if (v2 > vs[t] || (v2 == vs[t] && i2 < is[t])) { vs[t] = v2; is[t] = i2; }
    }
    __syncthreads();
  }
  if (t == 0) inp[b] = is[0];
}

// ---------------------------------------------------------------------------
// Init: h,c <- h0,c0 ; h split into hcat[:,0:1024]; combined bias; SOS inp.
// ---------------------------------------------------------------------------
__global__ __launch_bounds__(256) void init_kernel(
    const float* __restrict__ h0, const float* __restrict__ c0,
    float* h, float* c,
    const float* __restrict__ b_ih, const float* __restrict__ b_hh,
    float* bihh, int* inp,
    __bf16* __restrict__ hcat_h, __bf16* __restrict__ hcat_l)
{
  const int id = blockIdx.x * 256 + threadIdx.x;
  if (id < BB * HH) {
    const float hv = h0[id];
    h[id] = hv;
    c[id] = c0[id];
    __bf16 hh, hl;
    split1(hv, hh, hl);
    const int b = id >> 10, j = id & 1023;
    hcat_h[(size_t)b * 2048 + j] = hh;
    hcat_l[(size_t)b * 2048 + j] = hl;
  }
  if (id < 4096) bihh[id] = b_ih[id] + b_hh[id];
  if (id < BB) inp[id] = SOS;
}

extern "C" void kernel_launch(void* const* d_in, const int* in_sizes, int n_in,
                              void* d_out, int out_size, void* d_ws, size_t ws_size,
                              hipStream_t stream)
{
  (void)in_sizes; (void)n_in; (void)out_size; (void)ws_size;
  const float* enc      = (const float*)d_in[0];
  const float* h0       = (const float*)d_in[1];
  const float* c0       = (const float*)d_in[2];
  const float* emb      = (const float*)d_in[3];
  const float* W_ih     = (const float*)d_in[4];
  const float* W_hh     = (const float*)d_in[5];
  const float* b_ih     = (const float*)d_in[6];
  const float* b_hh     = (const float*)d_in[7];
  const float* attn_W   = (const float*)d_in[8];
  const float* attn_b   = (const float*)d_in[9];
  const float* concat_W = (const float*)d_in[10];
  const float* concat_b = (const float*)d_in[11];
  const float* lin_W    = (const float*)d_in[12];
  const float* lin_b    = (const float*)d_in[13];

  float* out = (float*)d_out;
  float* dec = out;                                  // [256][6][2048]
  float* h   = out + (size_t)BB * NSTEPS * VV;       // [256][1024]
  float* c   = h + (size_t)BB * HH;                  // [256][1024]
  float* wts = c + (size_t)BB * HH;                  // [256][512]

  char* w = (char*)d_ws;
  auto alloc = [&](size_t bytes) { char* p = w; w += (bytes + 255) & ~255ull; return p; };
  float*  bihh    = (float*)alloc(4096 * 4);
  int*    inp     = (int*)alloc(BB * 4);
  __bf16* Wcat_h  = (__bf16*)alloc((size_t)4096 * 2048 * 2);
  __bf16* Wcat_l  = (__bf16*)alloc((size_t)4096 * 2048 * 2);
  __bf16* attnW_h = (__bf16*)alloc((size_t)1024 * 1024 * 2);
  __bf16* attnW_l = (__bf16*)alloc((size_t)1024 * 1024 * 2);
  __bf16* catW_h  = (__bf16*)alloc((size_t)1024 * 2048 * 2);
  __bf16* catW_l  = (__bf16*)alloc((size_t)1024 * 2048 * 2);
  __bf16* linW_h  = (__bf16*)alloc((size_t)2048 * 1024 * 2);
  __bf16* linW_l  = (__bf16*)alloc((size_t)2048 * 1024 * 2);
  __bf16* emb_h   = (__bf16*)alloc((size_t)VV * HH * 2);
  __bf16* emb_l   = (__bf16*)alloc((size_t)VV * HH * 2);
  __bf16* hcat_h  = (__bf16*)alloc((size_t)BB * 2048 * 2);
  __bf16* hcat_l  = (__bf16*)alloc((size_t)BB * 2048 * 2);
  __bf16* co_h    = (__bf16*)alloc((size_t)BB * 1024 * 2);
  __bf16* co_l    = (__bf16*)alloc((size_t)BB * 1024 * 2);
  float*  pml     = (float*)alloc(BB * 4 * 4);
  float*  pcacc   = (float*)alloc((size_t)BB * 2 * HH * 4);
  float*  scb     = (float*)alloc((size_t)BB * SS * 4);
  float*  Pg      = (float*)alloc((size_t)2 * BB * 4096 * 4);  // gates partials
  float*  Pe      = (float*)alloc((size_t)4 * BB * 1024 * 4);  // energy partials
  float*  Pc      = (float*)alloc((size_t)4 * BB * 1024 * 4);  // concat partials
  float*  Pl      = (float*)alloc((size_t)2 * BB * 2048 * 4);  // logits partials

  conv_all<<<15360, 256, 0, stream>>>(W_ih, W_hh, attn_W, concat_W, lin_W, emb,
                                      Wcat_h, Wcat_l, attnW_h, attnW_l,
                                      catW_h, catW_l, linW_h, linW_l, emb_h, emb_l);
  init_kernel<<<1024, 256, 0, stream>>>(h0, c0, h, c, b_ih, b_hh, bihh, inp,
                                        hcat_h, hcat_l);

  for (int step = 0; step < NSTEPS; ++step) {
    // gates partials: [emb[inp]|h] @ Wcat^T, split-K2 (1024 each)
    gemm3<1><<<dim3(64, 4, 2), 256, 0, stream>>>(
        emb_h, emb_l, HH, hcat_h, hcat_l, inp, Wcat_h, Wcat_l, 2048,
        1024, Pg, 4096);
    lstm_reduce<<<1024, 256, 0, stream>>>(Pg, bihh, c, h, hcat_h, hcat_l);
    // energy partials: h @ attn_W^T, split-K4 (256 each)
    gemm3<0><<<dim3(16, 4, 4), 256, 0, stream>>>(
        hcat_h, hcat_l, 2048, nullptr, nullptr, nullptr, attnW_h, attnW_l, 1024,
        256, Pe, 1024);
    // fused energy-reduce + single-pass flash attention
    attn_part<<<2 * BB, 512, 0, stream>>>(Pe, attn_b, enc, pml, pcacc, scb);
    attn_merge<<<BB, 512, 0, stream>>>(pml, pcacc, scb, hcat_h, hcat_l, wts);
    // concat partials: [h|ctx] @ concat_W^T, split-K4 (512 each)
    gemm3<0><<<dim3(16, 4, 4), 256, 0, stream>>>(
        hcat_h, hcat_l, 2048, nullptr, nullptr, nullptr, catW_h, catW_l, 2048,
        512, Pc, 1024);
    co_reduce<<<256, 256, 0, stream>>>(Pc, concat_b, co_h, co_l);
    // logits partials: co @ lin_W^T, split-K2 (512 each)
    gemm3<0><<<dim3(32, 4, 2), 256, 0, stream>>>(
        co_h, co_l, 1024, nullptr, nullptr, nullptr, linW_h, linW_l, 1024,
        512, Pl, 2048);
    argmax_reduce<<<BB, 256, 0, stream>>>(Pl, lin_b, dec, step * VV, inp);
  }
}